// Round 6
// baseline (684.815 us; speedup 1.0000x reference)
//
#include <hip/hip_runtime.h>
#include <hip/hip_bf16.h>
#include <math.h>

#define B_ 8
#define N_ 2048
#define D_ 128
#define E_ 256
#define K_ 16
#define LN_EPS 1e-5f

typedef short bf16x8 __attribute__((ext_vector_type(8)));
typedef float f32x4 __attribute__((ext_vector_type(4)));

// ---------------------------------------------------------------------------
// Reference-matching f32 distance (expanded form, no FMA contraction).
// ---------------------------------------------------------------------------
__device__ __forceinline__ float sq3_ref(float x, float y, float z) {
#pragma clang fp contract(off)
    float s = x * x + y * y;
    s = s + z * z;
    return s;
}
__device__ __forceinline__ float d2_ref(float qx, float qy, float qz, float sqq,
                                        float mx, float my, float mz, float sqm) {
#pragma clang fp contract(off)
    float dot = mx * qx + my * qy;
    dot = dot + mz * qz;
    float t1 = sqq + sqm;
    float t2 = 2.0f * dot;
    float d2 = t1 - t2;
    return d2 > 0.0f ? d2 : 0.0f;
}

// pack two f32 -> bf16x2 dword; written so the compiler fuses to v_cvt_pk_bf16_f32
__device__ __forceinline__ unsigned pack2(float a, float b) {
    union { __hip_bfloat162 h2; unsigned u; } cv;
    cv.h2 = __float22bfloat162_rn(float2{a, b});
    return cv.u;
}

// exact-GELU via A&S 7.1.26 erf (|eps| < 1.5e-7), branchless
__device__ __forceinline__ float gelu_fast(float v) {
    const float z  = v * 0.70710678118654752440f;
    const float az = fabsf(z);
    const float t  = __fdividef(1.0f, fmaf(0.3275911f, az, 1.0f));
    float p = fmaf(1.061405429f, t, -1.453152027f);
    p = fmaf(p, t, 1.421413741f);
    p = fmaf(p, t, -0.284496736f);
    p = fmaf(p, t, 0.254829592f);
    p = p * t;
    const float ex = __expf(-az * az);
    float erfv = fmaf(-p, ex, 1.0f);
    erfv = (z < 0.0f) ? -erfv : erfv;
    return 0.5f * v * (1.0f + erfv);
}

// max over the 16 contiguous lanes of a DPP row (e = lane&15), VALU-only.
// xor1/xor2 via quad_perm; xor4 via half_mirror (valid: quad-uniform);
// xor8 via mirror (valid: 8-uniform).
__device__ __forceinline__ float dpp_rowmax16(float v) {
    int x = __float_as_int(v);
    v = fmaxf(v, __int_as_float(__builtin_amdgcn_mov_dpp(x, 0xB1, 0xF, 0xF, true)));
    x = __float_as_int(v);
    v = fmaxf(v, __int_as_float(__builtin_amdgcn_mov_dpp(x, 0x4E, 0xF, 0xF, true)));
    x = __float_as_int(v);
    v = fmaxf(v, __int_as_float(__builtin_amdgcn_mov_dpp(x, 0x141, 0xF, 0xF, true)));
    x = __float_as_int(v);
    v = fmaxf(v, __int_as_float(__builtin_amdgcn_mov_dpp(x, 0x140, 0xF, 0xF, true)));
    return v;
}

// ---------------------------------------------------------------------------
// Kernel 1: kNN top-16 via branch-free radix select (one wave per query).
// ---------------------------------------------------------------------------
__global__ __launch_bounds__(512) void knn_select_kernel(const float* __restrict__ coords,
                                                         int* __restrict__ knn_out) {
    __shared__ float lc[3][N_];
    __shared__ float lsq[N_];
    __shared__ int cnt[8];
    const int wave = threadIdx.x >> 6;
    const int lane = threadIdx.x & 63;
    const int p = blockIdx.x * 8 + wave;
    const int b = p >> 11;
    const int n0 = p & (N_ - 1);
    const float* cb = coords + (size_t)b * N_ * 3;
    for (int i = threadIdx.x; i < N_ * 3; i += 512) {
        int n = i / 3, c = i - 3 * n;
        lc[c][n] = cb[i];
    }
    __syncthreads();
    for (int n = threadIdx.x; n < N_; n += 512) lsq[n] = sq3_ref(lc[0][n], lc[1][n], lc[2][n]);
    __syncthreads();

    const float qx = lc[0][n0], qy = lc[1][n0], qz = lc[2][n0], sqq = lsq[n0];
    unsigned key[32];
#pragma unroll
    for (int j = 0; j < 32; ++j) {
        const int m = j * 64 + lane;
        key[j] = __float_as_uint(d2_ref(qx, qy, qz, sqq, lc[0][m], lc[1][m], lc[2][m], lsq[m]));
    }

    unsigned prefix = 0;
    int rem = K_, setc = N_, bshift = 0;
    bool bounded = false;
    for (int bit = 31; bit >= 0; --bit) {
        const unsigned want = prefix << 1;
        int c = 0;
#pragma unroll
        for (int j = 0; j < 32; ++j) c += ((key[j] >> bit) == want) ? 1 : 0;
        for (int off = 1; off < 64; off <<= 1) c += __shfl_xor(c, off, 64);
        if (rem <= c) { prefix = want; setc = c; }
        else          { prefix = want | 1u; rem -= c; setc -= c; }
        bshift = bit;
        if (setc == rem) { bounded = true; break; }
    }

    if (lane == 0) cnt[wave] = 0;
    int* op = knn_out + (size_t)p * K_;
    const unsigned long long BE = bounded ? (((unsigned long long)prefix + 1ull) << bshift)
                                          : (unsigned long long)prefix;
#pragma unroll
    for (int j = 0; j < 32; ++j) {
        if ((unsigned long long)key[j] < BE) {
            int s = atomicAdd(&cnt[wave], 1);
            op[s] = j * 64 + lane;
        }
    }
    if (!bounded) {
        const unsigned V = prefix;
#pragma unroll
        for (int j = 0; j < 32; ++j) {
            if (rem > 0) {
                unsigned long long mask = __ballot(key[j] == V);
                int below = __popcll(mask & ((1ull << lane) - 1ull));
                if (key[j] == V && below < rem) {
                    int s = atomicAdd(&cnt[wave], 1);
                    op[s] = j * 64 + lane;
                }
                rem -= __popcll(mask);
            }
        }
    }
}

// ---------------------------------------------------------------------------
// Kernel 2: prepack W1/W2/W3/Ws into bf16 MFMA A-fragments (fragment-linear):
//   fragment F = (L*8+kt)*16 + mt  (layers),  F = 384 + kt*16 + mt (Ws)
//   frag data [lane(g,e)][i] = W[32kt + 8g + i][16mt + e]
// 8 KiB stage-chunk c covers fragments [8c, 8c+8).
// ---------------------------------------------------------------------------
__global__ __launch_bounds__(64) void wprep_kernel(const float* __restrict__ W1,
                                                   const float* __restrict__ W2,
                                                   const float* __restrict__ W3,
                                                   const float* __restrict__ Ws,
                                                   short* __restrict__ WF) {
    const int bi = blockIdx.x;          // fragment index F, 0..447
    const int lane = threadIdx.x;
    const int g = lane >> 4, e = lane & 15;
    const float* W;
    int mt, kt;
    if (bi < 384) {
        const int L = bi >> 7;
        const int t = bi & 127;         // t = kt*16 + mt
        kt = t >> 4; mt = t & 15;
        W = (L == 0) ? W1 : (L == 1) ? W2 : W3;
    } else {
        const int t = bi - 384;
        kt = t >> 4; mt = t & 15;
        W = Ws;
    }
    const int f = 16 * mt + e;
    unsigned v[4];
#pragma unroll
    for (int i2 = 0; i2 < 4; ++i2) {
        const int k = 32 * kt + 8 * g + 2 * i2;
        v[i2] = pack2(W[(size_t)k * E_ + f], W[(size_t)(k + 1) * E_ + f]);
    }
    uint4 u; u.x = v[0]; u.y = v[1]; u.z = v[2]; u.w = v[3];
    *reinterpret_cast<uint4*>(WF + ((size_t)bi * 64 + lane) * 8) = u;
}

// ---------------------------------------------------------------------------
// Kernel 3: fused edge-MLP. 8 KiB W chunks staged to LDS (global_load_lds 16B),
// double-buffered, shared by 4 waves. 56 phases; per phase: {vmcnt(0);
// barrier; stage(c+1); 8 MFMA}. LDS total 49 KiB -> 3 blocks/CU.
// ---------------------------------------------------------------------------
#define WCHUNKS8 56

__device__ __forceinline__ void stage_chunk(const short* __restrict__ WF,
                                            short* __restrict__ dst,
                                            int c, int wave, int lane) {
    const short* src = WF + ((size_t)(c << 3) << 9);    // fragment 8c, *512 shorts
#pragma unroll
    for (int i = 0; i < 2; ++i) {
        const int slot = (i << 8) + (wave << 6);        // wave-uniform slot base
        const short* gp = src + ((size_t)(slot + lane) << 3);
        short* lp = dst + ((size_t)slot << 3);
        __builtin_amdgcn_global_load_lds(
            (const __attribute__((address_space(1))) void*)gp,
            (__attribute__((address_space(3))) void*)lp, 16, 0, 0);
    }
}

template <int LAST>
__device__ __forceinline__ void ln_gelu(f32x4 (&acc)[16], int e, int g,
                                        const float* __restrict__ bL,
                                        const float* __restrict__ gL,
                                        const float* __restrict__ beL,
                                        char* HB, unsigned swz) {
    float s = 0.f;
#pragma unroll
    for (int mt = 0; mt < 16; ++mt) {
        const float4 bv = *(const float4*)(bL + 16 * mt + 4 * g);
        acc[mt][0] += bv.x; acc[mt][1] += bv.y; acc[mt][2] += bv.z; acc[mt][3] += bv.w;
        s += acc[mt][0] + acc[mt][1] + acc[mt][2] + acc[mt][3];
    }
    s += __shfl_xor(s, 16, 64);
    s += __shfl_xor(s, 32, 64);
    const float mu = s * (1.0f / 256.0f);
    float q = 0.f;
#pragma unroll
    for (int mt = 0; mt < 16; ++mt) {
#pragma unroll
        for (int i = 0; i < 4; ++i) { const float d = acc[mt][i] - mu; q = fmaf(d, d, q); }
    }
    q += __shfl_xor(q, 16, 64);
    q += __shfl_xor(q, 32, 64);
    const float rstd = rsqrtf(q * (1.0f / 256.0f) + LN_EPS);
#pragma unroll
    for (int mt = 0; mt < 16; ++mt) {
        const float4 gv  = *(const float4*)(gL + 16 * mt + 4 * g);
        const float4 bev = *(const float4*)(beL + 16 * mt + 4 * g);
        const float r0 = gelu_fast(fmaf((acc[mt][0] - mu) * rstd, gv.x, bev.x));
        const float r1 = gelu_fast(fmaf((acc[mt][1] - mu) * rstd, gv.y, bev.y));
        const float r2 = gelu_fast(fmaf((acc[mt][2] - mu) * rstd, gv.z, bev.z));
        const float r3 = gelu_fast(fmaf((acc[mt][3] - mu) * rstd, gv.w, bev.w));
        if (LAST) {
            acc[mt][0] = r0; acc[mt][1] = r1; acc[mt][2] = r2; acc[mt][3] = r3;
        } else {
            *(uint2*)(HB + (((e << 9) + (mt << 5) + (g << 3)) ^ swz)) =
                make_uint2(pack2(r0, r1), pack2(r2, r3));
        }
    }
}

__global__ __launch_bounds__(256, 3) void edgeconv_mfma(
    const float* __restrict__ x, const int* __restrict__ knn,
    const short* __restrict__ WF,
    const float* __restrict__ b1, const float* __restrict__ g1, const float* __restrict__ be1,
    const float* __restrict__ b2, const float* __restrict__ g2, const float* __restrict__ be2,
    const float* __restrict__ b3, const float* __restrict__ g3, const float* __restrict__ be3,
    const float* __restrict__ bs,
    float* __restrict__ out)
{
    __shared__ short Hl[4][4096];       // 32 KiB: 4 waves x (16x256 bf16), XOR-swizzled
    __shared__ short Wbuf[2][4096];     // 16 KiB: double-buffered 8 KiB W chunks
    __shared__ short Hx[4][128];        // 1 KiB: broadcast bf16 x-row per wave
    const int tid  = threadIdx.x;
    const int wave = tid >> 6;
    const int lane = tid & 63;
    const int e = lane & 15;
    const int g = lane >> 4;
    const int p = blockIdx.x * 4 + wave;
    const int b = p >> 11;
    const int n = p & (N_ - 1);
    const unsigned swz = (unsigned)((e & 7) << 4);
    char* H0 = (char*)&Hl[wave][0];
    char* XC = (char*)&Hx[wave][0];

    // issue chunk-0 staging first so it flies under the H build
    stage_chunk(WF, &Wbuf[0][0], 0, wave, lane);

    // ---- edge build: H[e][0:128]=central, H[e][128:256]=nbr-central
    {
        const float4* xr = (const float4*)(x + ((size_t)b * N_ + n) * D_);
        const int nb = knn[(size_t)p * K_ + e];
        const float4* nr = (const float4*)(x + ((size_t)b * N_ + nb) * D_);
#pragma unroll
        for (int c2 = 0; c2 < 8; ++c2) {
            const float4 cv = xr[8 * g + c2];
            const float4 nv = nr[8 * g + c2];
            const int base = (e << 9) + (g << 6) + (c2 << 3);
            const uint2 cpk = make_uint2(pack2(cv.x, cv.y), pack2(cv.z, cv.w));
            *(uint2*)(H0 + (base ^ swz)) = cpk;
            *(uint2*)(H0 + ((base + 256) ^ swz)) =
                make_uint2(pack2(nv.x - cv.x, nv.y - cv.y), pack2(nv.z - cv.z, nv.w - cv.w));
            if (e == 0) *(uint2*)(XC + (g << 6) + (c2 << 3)) = cpk;
        }
    }

    f32x4 acc[16];
    int pb = 0;                                      // current W buffer parity
    const f32x4 z = {0.f, 0.f, 0.f, 0.f};

    for (int L = 0; L < 3; ++L) {
        const float* bL  = (L == 0) ? b1  : (L == 1) ? b2  : b3;
        const float* gL  = (L == 0) ? g1  : (L == 1) ? g2  : g3;
        const float* beL = (L == 0) ? be1 : (L == 1) ? be2 : be3;

#pragma unroll
        for (int mt = 0; mt < 16; ++mt) acc[mt] = z;

        for (int kt = 0; kt < 8; ++kt) {
            const int c = (L * 8 + kt) * 2;
            // ---- half 0: fragments mt 0..7
            asm volatile("s_waitcnt vmcnt(0)" ::: "memory");
            __syncthreads();
            stage_chunk(WF, &Wbuf[pb ^ 1][0], c + 1, wave, lane);
            const bf16x8 Bc = *(const bf16x8*)(H0 + (((e << 9) + (kt << 6) + (g << 4)) ^ swz));
            {
                const short* Wc = &Wbuf[pb][0];
#pragma unroll
                for (int mtl = 0; mtl < 8; ++mtl) {
                    const bf16x8 a = *(const bf16x8*)(Wc + (((mtl << 6) + lane) << 3));
                    acc[mtl] = __builtin_amdgcn_mfma_f32_16x16x32_bf16(a, Bc, acc[mtl], 0, 0, 0);
                }
            }
            pb ^= 1;
            // ---- half 1: fragments mt 8..15
            asm volatile("s_waitcnt vmcnt(0)" ::: "memory");
            __syncthreads();
            if (c + 2 < WCHUNKS8) stage_chunk(WF, &Wbuf[pb ^ 1][0], c + 2, wave, lane);
            {
                const short* Wc = &Wbuf[pb][0];
#pragma unroll
                for (int mtl = 0; mtl < 8; ++mtl) {
                    const bf16x8 a = *(const bf16x8*)(Wc + (((mtl << 6) + lane) << 3));
                    acc[8 + mtl] = __builtin_amdgcn_mfma_f32_16x16x32_bf16(a, Bc, acc[8 + mtl], 0, 0, 0);
                }
            }
            pb ^= 1;
        }

        if (L < 2) {
            ln_gelu<0>(acc, e, g, bL, gL, beL, H0, swz);
            asm volatile("s_waitcnt lgkmcnt(0)" ::: "memory");
        } else {
            ln_gelu<1>(acc, e, g, bL, gL, beL, H0, swz);
        }
    }

    // ---- max over 16 edges: DPP row-reduce (VALU only, no DS) ----
#pragma unroll
    for (int mt = 0; mt < 16; ++mt) {
#pragma unroll
        for (int i = 0; i < 4; ++i) acc[mt][i] = dpp_rowmax16(acc[mt][i]);
    }
    f32x4 sel = acc[0];
#pragma unroll
    for (int mt = 1; mt < 16; ++mt) {
        if (e == mt) sel = acc[mt];
    }

    // ---- shortcut x @ Ws via MFMA (chunks 48..55), REUSING acc ----
#pragma unroll
    for (int mt = 0; mt < 16; ++mt) acc[mt] = z;
    for (int kt = 0; kt < 4; ++kt) {
        const bf16x8 bx = *(const bf16x8*)(XC + (kt << 6) + (g << 4));
#pragma unroll
        for (int half = 0; half < 2; ++half) {
            const int c = 48 + kt * 2 + half;
            asm volatile("s_waitcnt vmcnt(0)" ::: "memory");
            __syncthreads();
            if (c + 1 < WCHUNKS8) stage_chunk(WF, &Wbuf[pb ^ 1][0], c + 1, wave, lane);
            const short* Wc = &Wbuf[pb][0];
#pragma unroll
            for (int mtl = 0; mtl < 8; ++mtl) {
                const bf16x8 a = *(const bf16x8*)(Wc + (((mtl << 6) + lane) << 3));
                acc[half * 8 + mtl] =
                    __builtin_amdgcn_mfma_f32_16x16x32_bf16(a, bx, acc[half * 8 + mtl], 0, 0, 0);
            }
            pb ^= 1;
        }
    }
    f32x4 ssc = acc[0];
#pragma unroll
    for (int mt = 1; mt < 16; ++mt) {
        if (e == mt) ssc = acc[mt];
    }

    const int f0 = 16 * e + 4 * g;
    const float4 bsv = *(const float4*)(bs + f0);
    float4 o;
    o.x = gelu_fast(sel[0] + ssc[0] + bsv.x);
    o.y = gelu_fast(sel[1] + ssc[1] + bsv.y);
    o.z = gelu_fast(sel[2] + ssc[2] + bsv.z);
    o.w = gelu_fast(sel[3] + ssc[3] + bsv.w);
    *(float4*)(out + (size_t)p * E_ + f0) = o;
}

extern "C" void kernel_launch(void* const* d_in, const int* in_sizes, int n_in,
                              void* d_out, int out_size, void* d_ws, size_t ws_size,
                              hipStream_t stream) {
    const float* x      = (const float*)d_in[0];
    const float* coords = (const float*)d_in[1];
    const float* W1  = (const float*)d_in[2];
    const float* b1  = (const float*)d_in[3];
    const float* g1  = (const float*)d_in[4];
    const float* be1 = (const float*)d_in[5];
    const float* W2  = (const float*)d_in[6];
    const float* b2  = (const float*)d_in[7];
    const float* g2  = (const float*)d_in[8];
    const float* be2 = (const float*)d_in[9];
    const float* W3  = (const float*)d_in[10];
    const float* b3  = (const float*)d_in[11];
    const float* g3  = (const float*)d_in[12];
    const float* be3 = (const float*)d_in[13];
    const float* Ws  = (const float*)d_in[14];
    const float* bs  = (const float*)d_in[15];
    float* out = (float*)d_out;

    int*   knn = (int*)d_ws;                          // 1 MiB
    short* WF  = (short*)((char*)d_ws + (1 << 20));   // 448 KiB bf16 fragments

    wprep_kernel<<<448, 64, 0, stream>>>(W1, W2, W3, Ws, WF);
    knn_select_kernel<<<B_ * (N_ / 8), 512, 0, stream>>>(coords, knn);
    edgeconv_mfma<<<(B_ * N_) / 4, 256, 0, stream>>>(
        x, knn, WF, b1, g1, be1, b2, g2, be2, b3, g3, be3, bs, out);
}

// Round 7
// 442.152 us; speedup vs baseline: 1.5488x; 1.5488x over previous
//
#include <hip/hip_runtime.h>
#include <hip/hip_bf16.h>
#include <math.h>

#define B_ 8
#define N_ 2048
#define D_ 128
#define E_ 256
#define K_ 16
#define LN_EPS 1e-5f

typedef short bf16x8 __attribute__((ext_vector_type(8)));
typedef float f32x4 __attribute__((ext_vector_type(4)));

// ---------------------------------------------------------------------------
// Reference-matching f32 distance (expanded form, no FMA contraction).
// ---------------------------------------------------------------------------
__device__ __forceinline__ float sq3_ref(float x, float y, float z) {
#pragma clang fp contract(off)
    float s = x * x + y * y;
    s = s + z * z;
    return s;
}
__device__ __forceinline__ float d2_ref(float qx, float qy, float qz, float sqq,
                                        float mx, float my, float mz, float sqm) {
#pragma clang fp contract(off)
    float dot = mx * qx + my * qy;
    dot = dot + mz * qz;
    float t1 = sqq + sqm;
    float t2 = 2.0f * dot;
    float d2 = t1 - t2;
    return d2 > 0.0f ? d2 : 0.0f;
}

// pack two f32 -> bf16x2 dword (compiler fuses to v_cvt_pk_bf16_f32)
__device__ __forceinline__ unsigned pack2(float a, float b) {
    union { __hip_bfloat162 h2; unsigned u; } cv;
    cv.h2 = __float22bfloat162_rn(float2{a, b});
    return cv.u;
}

// tanh-form GELU via sigmoid identity: gelu(v) = v * sigmoid(2u),
// u = 0.7978845608 v (1 + 0.044715 v^2).  |err vs exact erf-GELU| <~ 1e-3.
// Saturation-safe: exp overflow -> v/inf -> 0 (correct sign side).
__device__ __forceinline__ float gelu_fast(float v) {
    const float w = v * v;
    const float inner = fmaf(0.044715f, w, 1.0f);
    const float ue = (v * -1.5957691216f) * inner;   // -2u
    const float t = __expf(ue);
    return __fdividef(v, 1.0f + t);
}

// max over the 16 contiguous lanes of a DPP row (e = lane&15), VALU-only.
__device__ __forceinline__ float dpp_rowmax16(float v) {
    int x = __float_as_int(v);
    v = fmaxf(v, __int_as_float(__builtin_amdgcn_mov_dpp(x, 0xB1, 0xF, 0xF, true)));
    x = __float_as_int(v);
    v = fmaxf(v, __int_as_float(__builtin_amdgcn_mov_dpp(x, 0x4E, 0xF, 0xF, true)));
    x = __float_as_int(v);
    v = fmaxf(v, __int_as_float(__builtin_amdgcn_mov_dpp(x, 0x141, 0xF, 0xF, true)));
    x = __float_as_int(v);
    v = fmaxf(v, __int_as_float(__builtin_amdgcn_mov_dpp(x, 0x140, 0xF, 0xF, true)));
    return v;
}

// ---------------------------------------------------------------------------
// Kernel 1: kNN top-16 via branch-free radix select (one wave per query).
// ---------------------------------------------------------------------------
__global__ __launch_bounds__(512) void knn_select_kernel(const float* __restrict__ coords,
                                                         int* __restrict__ knn_out) {
    __shared__ float lc[3][N_];
    __shared__ float lsq[N_];
    __shared__ int cnt[8];
    const int wave = threadIdx.x >> 6;
    const int lane = threadIdx.x & 63;
    const int p = blockIdx.x * 8 + wave;
    const int b = p >> 11;
    const int n0 = p & (N_ - 1);
    const float* cb = coords + (size_t)b * N_ * 3;
    for (int i = threadIdx.x; i < N_ * 3; i += 512) {
        int n = i / 3, c = i - 3 * n;
        lc[c][n] = cb[i];
    }
    __syncthreads();
    for (int n = threadIdx.x; n < N_; n += 512) lsq[n] = sq3_ref(lc[0][n], lc[1][n], lc[2][n]);
    __syncthreads();

    const float qx = lc[0][n0], qy = lc[1][n0], qz = lc[2][n0], sqq = lsq[n0];
    unsigned key[32];
#pragma unroll
    for (int j = 0; j < 32; ++j) {
        const int m = j * 64 + lane;
        key[j] = __float_as_uint(d2_ref(qx, qy, qz, sqq, lc[0][m], lc[1][m], lc[2][m], lsq[m]));
    }

    unsigned prefix = 0;
    int rem = K_, setc = N_, bshift = 0;
    bool bounded = false;
    for (int bit = 31; bit >= 0; --bit) {
        const unsigned want = prefix << 1;
        int c = 0;
#pragma unroll
        for (int j = 0; j < 32; ++j) c += ((key[j] >> bit) == want) ? 1 : 0;
        for (int off = 1; off < 64; off <<= 1) c += __shfl_xor(c, off, 64);
        if (rem <= c) { prefix = want; setc = c; }
        else          { prefix = want | 1u; rem -= c; setc -= c; }
        bshift = bit;
        if (setc == rem) { bounded = true; break; }
    }

    if (lane == 0) cnt[wave] = 0;
    int* op = knn_out + (size_t)p * K_;
    const unsigned long long BE = bounded ? (((unsigned long long)prefix + 1ull) << bshift)
                                          : (unsigned long long)prefix;
#pragma unroll
    for (int j = 0; j < 32; ++j) {
        if ((unsigned long long)key[j] < BE) {
            int s = atomicAdd(&cnt[wave], 1);
            op[s] = j * 64 + lane;
        }
    }
    if (!bounded) {
        const unsigned V = prefix;
#pragma unroll
        for (int j = 0; j < 32; ++j) {
            if (rem > 0) {
                unsigned long long mask = __ballot(key[j] == V);
                int below = __popcll(mask & ((1ull << lane) - 1ull));
                if (key[j] == V && below < rem) {
                    int s = atomicAdd(&cnt[wave], 1);
                    op[s] = j * 64 + lane;
                }
                rem -= __popcll(mask);
            }
        }
    }
}

// ---------------------------------------------------------------------------
// Kernel 2: prepack W1/W2/W3/Ws into bf16 MFMA A-fragments, CHUNK-MAJOR:
// chunk c (16 KiB) = fragments [16c..16c+15]; fragment (c,mt):
//   W[32kt + 8g + i][16mt + e],  c = L*8+kt (layers), 24+kt (Ws, kt<4).
// ---------------------------------------------------------------------------
__global__ __launch_bounds__(64) void wprep_kernel(const float* __restrict__ W1,
                                                   const float* __restrict__ W2,
                                                   const float* __restrict__ W3,
                                                   const float* __restrict__ Ws,
                                                   short* __restrict__ WF) {
    const int bi = blockIdx.x;          // 0..447
    const int lane = threadIdx.x;
    const int g = lane >> 4, e = lane & 15;
    const float* W;
    int mt, kt;
    if (bi < 384) {
        const int L = bi >> 7;
        const int t = bi & 127;         // t = kt*16 + mt
        kt = t >> 4; mt = t & 15;
        W = (L == 0) ? W1 : (L == 1) ? W2 : W3;
    } else {
        const int t = bi - 384;
        kt = t >> 4; mt = t & 15;
        W = Ws;
    }
    const int f = 16 * mt + e;
    unsigned v[4];
#pragma unroll
    for (int i2 = 0; i2 < 4; ++i2) {
        const int k = 32 * kt + 8 * g + 2 * i2;
        v[i2] = pack2(W[(size_t)k * E_ + f], W[(size_t)(k + 1) * E_ + f]);
    }
    uint4 u; u.x = v[0]; u.y = v[1]; u.z = v[2]; u.w = v[3];
    *reinterpret_cast<uint4*>(WF + ((size_t)bi * 64 + lane) * 8) = u;
}

// ---------------------------------------------------------------------------
// Kernel 3: fused edge-MLP (R5 structure). 16 KiB W chunks staged to LDS via
// global_load_lds (16B), double-buffered, shared by 4 waves; 28 phases of
// {vmcnt(0); barrier; stage(c+1); 16 MFMA}. LN params staged in LDS.
// ---------------------------------------------------------------------------
#define WCHUNKS 28

__device__ __forceinline__ void stage_chunk(const short* __restrict__ WF,
                                            short* __restrict__ dst,
                                            int c, int wave, int lane) {
    const short* src = WF + ((size_t)(c << 4) << 9);    // fragment 16c, *512 shorts
#pragma unroll
    for (int i = 0; i < 4; ++i) {
        const int slot = (i << 8) + (wave << 6);        // wave-uniform slot base
        const short* gp = src + ((size_t)(slot + lane) << 3);
        short* lp = dst + ((size_t)slot << 3);
        __builtin_amdgcn_global_load_lds(
            (const __attribute__((address_space(1))) void*)gp,
            (__attribute__((address_space(3))) void*)lp, 16, 0, 0);
    }
}

// One-pass LN (E[x^2]-mu^2) + fused scale + fast GELU. Params from LDS (PlL).
template <int LAST>
__device__ __forceinline__ void ln_gelu(f32x4 (&acc)[16], int e, int g,
                                        const float* __restrict__ PlL,
                                        char* HB, unsigned swz) {
    float s = 0.f, q = 0.f;
#pragma unroll
    for (int mt = 0; mt < 16; ++mt) {
        const float4 bv = *(const float4*)(PlL + mt * 16 + (g << 2));   // bias
        acc[mt][0] += bv.x; acc[mt][1] += bv.y; acc[mt][2] += bv.z; acc[mt][3] += bv.w;
        s += (acc[mt][0] + acc[mt][1]) + (acc[mt][2] + acc[mt][3]);
        q = fmaf(acc[mt][0], acc[mt][0], q); q = fmaf(acc[mt][1], acc[mt][1], q);
        q = fmaf(acc[mt][2], acc[mt][2], q); q = fmaf(acc[mt][3], acc[mt][3], q);
    }
    s += __shfl_xor(s, 16, 64);
    s += __shfl_xor(s, 32, 64);
    q += __shfl_xor(q, 16, 64);
    q += __shfl_xor(q, 32, 64);
    const float mu = s * (1.0f / 256.0f);
    const float var = fmaf(-mu, mu, q * (1.0f / 256.0f));
    const float rstd = rsqrtf(var + LN_EPS);
#pragma unroll
    for (int mt = 0; mt < 16; ++mt) {
        const float4 gv  = *(const float4*)(PlL + 256 + mt * 16 + (g << 2));
        const float4 bev = *(const float4*)(PlL + 512 + mt * 16 + (g << 2));
        const float A0 = rstd * gv.x, A1 = rstd * gv.y, A2 = rstd * gv.z, A3 = rstd * gv.w;
        const float r0 = gelu_fast(fmaf(acc[mt][0], A0, fmaf(-mu, A0, bev.x)));
        const float r1 = gelu_fast(fmaf(acc[mt][1], A1, fmaf(-mu, A1, bev.y)));
        const float r2 = gelu_fast(fmaf(acc[mt][2], A2, fmaf(-mu, A2, bev.z)));
        const float r3 = gelu_fast(fmaf(acc[mt][3], A3, fmaf(-mu, A3, bev.w)));
        if (LAST) {
            acc[mt][0] = r0; acc[mt][1] = r1; acc[mt][2] = r2; acc[mt][3] = r3;
        } else {
            *(uint2*)(HB + (((e << 9) + (mt << 5) + (g << 3)) ^ swz)) =
                make_uint2(pack2(r0, r1), pack2(r2, r3));
        }
    }
}

__global__ __launch_bounds__(256, 2) void edgeconv_mfma(
    const float* __restrict__ x, const int* __restrict__ knn,
    const short* __restrict__ WF,
    const float* __restrict__ b1, const float* __restrict__ g1, const float* __restrict__ be1,
    const float* __restrict__ b2, const float* __restrict__ g2, const float* __restrict__ be2,
    const float* __restrict__ b3, const float* __restrict__ g3, const float* __restrict__ be3,
    const float* __restrict__ bs,
    float* __restrict__ out)
{
    __shared__ short Hl[4][4096];       // 32 KiB: 4 waves x (16x256 bf16), XOR-swizzled
    __shared__ short Wbuf[2][8192];     // 32 KiB: double-buffered 16 KiB W chunks
    __shared__ short Hx[4][128];        // 1 KiB: broadcast bf16 x-row per wave
    __shared__ float Pl[9 * 256];       // 9 KiB: b1,g1,be1,b2,g2,be2,b3,g3,be3
    const int tid  = threadIdx.x;
    const int wave = tid >> 6;
    const int lane = tid & 63;
    const int e = lane & 15;
    const int g = lane >> 4;
    const int p = blockIdx.x * 4 + wave;
    const int b = p >> 11;
    const int n = p & (N_ - 1);
    const unsigned swz = (unsigned)((e & 7) << 4);
    char* H0 = (char*)&Hl[wave][0];
    char* XC = (char*)&Hx[wave][0];

    // issue chunk-0 staging first so it flies under the H build
    stage_chunk(WF, &Wbuf[0][0], 0, wave, lane);

    // stage LN params once per block (visible after the phase-0 barrier chain)
    {
        const float* srcs[9] = {b1, g1, be1, b2, g2, be2, b3, g3, be3};
#pragma unroll
        for (int a = 0; a < 9; ++a) Pl[a * 256 + tid] = srcs[a][tid];
    }

    // ---- edge build: H[e][0:128]=central, H[e][128:256]=nbr-central
    {
        const float4* xr = (const float4*)(x + ((size_t)b * N_ + n) * D_);
        const int nb = knn[(size_t)p * K_ + e];
        const float4* nr = (const float4*)(x + ((size_t)b * N_ + nb) * D_);
#pragma unroll
        for (int c2 = 0; c2 < 8; ++c2) {
            const float4 cv = xr[8 * g + c2];
            const float4 nv = nr[8 * g + c2];
            const int base = (e << 9) + (g << 6) + (c2 << 3);
            const uint2 cpk = make_uint2(pack2(cv.x, cv.y), pack2(cv.z, cv.w));
            *(uint2*)(H0 + (base ^ swz)) = cpk;
            *(uint2*)(H0 + ((base + 256) ^ swz)) =
                make_uint2(pack2(nv.x - cv.x, nv.y - cv.y), pack2(nv.z - cv.z, nv.w - cv.w));
            if (e == 0) *(uint2*)(XC + (g << 6) + (c2 << 3)) = cpk;
        }
    }

    f32x4 acc[16];
    int pb = 0;                                      // current W buffer parity
    const f32x4 z = {0.f, 0.f, 0.f, 0.f};

    for (int L = 0; L < 3; ++L) {
        const float* PlL = &Pl[L * 768];
#pragma unroll
        for (int mt = 0; mt < 16; ++mt) acc[mt] = z;

        for (int kt = 0; kt < 8; ++kt) {
            const int c = L * 8 + kt;
            asm volatile("s_waitcnt vmcnt(0)" ::: "memory");   // our stage loads of c done
            __syncthreads();                                    // c visible; prev buf free
            if (c + 1 < WCHUNKS) stage_chunk(WF, &Wbuf[pb ^ 1][0], c + 1, wave, lane);
            const bf16x8 Bc = *(const bf16x8*)(H0 + (((e << 9) + (kt << 6) + (g << 4)) ^ swz));
            const short* Wc = &Wbuf[pb][0];
            __builtin_amdgcn_s_setprio(1);
#pragma unroll
            for (int mt = 0; mt < 16; ++mt) {
                const bf16x8 a = *(const bf16x8*)(Wc + (((mt << 6) + lane) << 3));
                acc[mt] = __builtin_amdgcn_mfma_f32_16x16x32_bf16(a, Bc, acc[mt], 0, 0, 0);
            }
            __builtin_amdgcn_s_setprio(0);
            pb ^= 1;
        }

        if (L < 2) {
            ln_gelu<0>(acc, e, g, PlL, H0, swz);
            asm volatile("s_waitcnt lgkmcnt(0)" ::: "memory");
        } else {
            ln_gelu<1>(acc, e, g, PlL, H0, swz);
        }
    }

    // ---- max over 16 edges: DPP row-reduce (VALU only) ----
#pragma unroll
    for (int mt = 0; mt < 16; ++mt) {
#pragma unroll
        for (int i = 0; i < 4; ++i) acc[mt][i] = dpp_rowmax16(acc[mt][i]);
    }
    // ---- dynamic-index select sel = acc[e] via LDS bounce (H region is dead)
    float* Sb = (float*)H0;
#pragma unroll
    for (int mt = 0; mt < 16; ++mt) {
        if (e == mt) *(float4*)&Sb[mt * 16 + (g << 2)] = *(const float4*)&acc[mt];
    }
    asm volatile("s_waitcnt lgkmcnt(0)" ::: "memory");
    const float4 sel = *(const float4*)&Sb[e * 16 + (g << 2)];

    // ---- shortcut x @ Ws via MFMA (chunks 24..27), REUSING acc ----
#pragma unroll
    for (int mt = 0; mt < 16; ++mt) acc[mt] = z;
    for (int kt = 0; kt < 4; ++kt) {
        const int c = 24 + kt;
        asm volatile("s_waitcnt vmcnt(0)" ::: "memory");
        __syncthreads();
        if (c + 1 < WCHUNKS) stage_chunk(WF, &Wbuf[pb ^ 1][0], c + 1, wave, lane);
        const bf16x8 bx = *(const bf16x8*)(XC + (kt << 6) + (g << 4));
        const short* Wc = &Wbuf[pb][0];
        __builtin_amdgcn_s_setprio(1);
#pragma unroll
        for (int mt = 0; mt < 16; ++mt) {
            const bf16x8 a = *(const bf16x8*)(Wc + (((mt << 6) + lane) << 3));
            acc[mt] = __builtin_amdgcn_mfma_f32_16x16x32_bf16(a, bx, acc[mt], 0, 0, 0);
        }
        __builtin_amdgcn_s_setprio(0);
        pb ^= 1;
    }
    // shortcut columns are identical (broadcast B) -> no reduce, just select
#pragma unroll
    for (int mt = 0; mt < 16; ++mt) {
        if (e == mt) *(float4*)&Sb[mt * 16 + (g << 2)] = *(const float4*)&acc[mt];
    }
    asm volatile("s_waitcnt lgkmcnt(0)" ::: "memory");
    const float4 ssc = *(const float4*)&Sb[e * 16 + (g << 2)];

    const int f0 = 16 * e + 4 * g;
    const float4 bsv = *(const float4*)(bs + f0);
    float4 o;
    o.x = gelu_fast(sel.x + ssc.x + bsv.x);
    o.y = gelu_fast(sel.y + ssc.y + bsv.y);
    o.z = gelu_fast(sel.z + ssc.z + bsv.z);
    o.w = gelu_fast(sel.w + ssc.w + bsv.w);
    *(float4*)(out + (size_t)p * E_ + f0) = o;
}

extern "C" void kernel_launch(void* const* d_in, const int* in_sizes, int n_in,
                              void* d_out, int out_size, void* d_ws, size_t ws_size,
                              hipStream_t stream) {
    const float* x      = (const float*)d_in[0];
    const float* coords = (const float*)d_in[1];
    const float* W1  = (const float*)d_in[2];
    const float* b1  = (const float*)d_in[3];
    const float* g1  = (const float*)d_in[4];
    const float* be1 = (const float*)d_in[5];
    const float* W2  = (const float*)d_in[6];
    const float* b2  = (const float*)d_in[7];
    const float* g2  = (const float*)d_in[8];
    const float* be2 = (const float*)d_in[9];
    const float* W3  = (const float*)d_in[10];
    const float* b3  = (const float*)d_in[11];
    const float* g3  = (const float*)d_in[12];
    const float* be3 = (const float*)d_in[13];
    const float* Ws  = (const float*)d_in[14];
    const float* bs  = (const float*)d_in[15];
    float* out = (float*)d_out;

    int*   knn = (int*)d_ws;                          // 1 MiB
    short* WF  = (short*)((char*)d_ws + (1 << 20));   // 448 KiB bf16 fragments

    wprep_kernel<<<448, 64, 0, stream>>>(W1, W2, W3, Ws, WF);
    knn_select_kernel<<<B_ * (N_ / 8), 512, 0, stream>>>(coords, knn);
    edgeconv_mfma<<<(B_ * N_) / 4, 256, 0, stream>>>(
        x, knn, WF, b1, g1, be1, b2, g2, be2, b3, g3, be3, bs, out);
}

// Round 8
// 388.644 us; speedup vs baseline: 1.7621x; 1.1377x over previous
//
#include <hip/hip_runtime.h>
#include <hip/hip_bf16.h>
#include <math.h>

#define B_ 8
#define N_ 2048
#define D_ 128
#define E_ 256
#define K_ 16
#define LN_EPS 1e-5f

typedef short bf16x8 __attribute__((ext_vector_type(8)));
typedef float f32x4 __attribute__((ext_vector_type(4)));

// ---------------------------------------------------------------------------
// Reference-matching f32 distance (expanded form, no FMA contraction).
// ---------------------------------------------------------------------------
__device__ __forceinline__ float sq3_ref(float x, float y, float z) {
#pragma clang fp contract(off)
    float s = x * x + y * y;
    s = s + z * z;
    return s;
}
__device__ __forceinline__ float d2_ref(float qx, float qy, float qz, float sqq,
                                        float mx, float my, float mz, float sqm) {
#pragma clang fp contract(off)
    float dot = mx * qx + my * qy;
    dot = dot + mz * qz;
    float t1 = sqq + sqm;
    float t2 = 2.0f * dot;
    float d2 = t1 - t2;
    return d2 > 0.0f ? d2 : 0.0f;
}

// pack two f32 -> bf16x2 dword (compiler fuses to v_cvt_pk_bf16_f32)
__device__ __forceinline__ unsigned pack2(float a, float b) {
    union { __hip_bfloat162 h2; unsigned u; } cv;
    cv.h2 = __float22bfloat162_rn(float2{a, b});
    return cv.u;
}

// tanh-form GELU via sigmoid identity: gelu(v) = v * sigmoid(2u),
// u = 0.7978845608 v (1 + 0.044715 v^2).  |err vs exact erf-GELU| <~ 1e-3.
__device__ __forceinline__ float gelu_fast(float v) {
    const float w = v * v;
    const float inner = fmaf(0.044715f, w, 1.0f);
    const float ue = (v * -1.5957691216f) * inner;   // -2u
    const float t = __expf(ue);
    return __fdividef(v, 1.0f + t);
}

// max over the 16 contiguous lanes of a DPP row (e = lane&15), VALU-only.
__device__ __forceinline__ float dpp_rowmax16(float v) {
    int x = __float_as_int(v);
    v = fmaxf(v, __int_as_float(__builtin_amdgcn_mov_dpp(x, 0xB1, 0xF, 0xF, true)));
    x = __float_as_int(v);
    v = fmaxf(v, __int_as_float(__builtin_amdgcn_mov_dpp(x, 0x4E, 0xF, 0xF, true)));
    x = __float_as_int(v);
    v = fmaxf(v, __int_as_float(__builtin_amdgcn_mov_dpp(x, 0x141, 0xF, 0xF, true)));
    x = __float_as_int(v);
    v = fmaxf(v, __int_as_float(__builtin_amdgcn_mov_dpp(x, 0x140, 0xF, 0xF, true)));
    return v;
}

// ---------------------------------------------------------------------------
// Kernel 1: kNN top-16 via branch-free radix select (one wave per query).
// ---------------------------------------------------------------------------
__global__ __launch_bounds__(512) void knn_select_kernel(const float* __restrict__ coords,
                                                         int* __restrict__ knn_out) {
    __shared__ float lc[3][N_];
    __shared__ float lsq[N_];
    __shared__ int cnt[8];
    const int wave = threadIdx.x >> 6;
    const int lane = threadIdx.x & 63;
    const int p = blockIdx.x * 8 + wave;
    const int b = p >> 11;
    const int n0 = p & (N_ - 1);
    const float* cb = coords + (size_t)b * N_ * 3;
    for (int i = threadIdx.x; i < N_ * 3; i += 512) {
        int n = i / 3, c = i - 3 * n;
        lc[c][n] = cb[i];
    }
    __syncthreads();
    for (int n = threadIdx.x; n < N_; n += 512) lsq[n] = sq3_ref(lc[0][n], lc[1][n], lc[2][n]);
    __syncthreads();

    const float qx = lc[0][n0], qy = lc[1][n0], qz = lc[2][n0], sqq = lsq[n0];
    unsigned key[32];
#pragma unroll
    for (int j = 0; j < 32; ++j) {
        const int m = j * 64 + lane;
        key[j] = __float_as_uint(d2_ref(qx, qy, qz, sqq, lc[0][m], lc[1][m], lc[2][m], lsq[m]));
    }

    unsigned prefix = 0;
    int rem = K_, setc = N_, bshift = 0;
    bool bounded = false;
    for (int bit = 31; bit >= 0; --bit) {
        const unsigned want = prefix << 1;
        int c = 0;
#pragma unroll
        for (int j = 0; j < 32; ++j) c += ((key[j] >> bit) == want) ? 1 : 0;
        for (int off = 1; off < 64; off <<= 1) c += __shfl_xor(c, off, 64);
        if (rem <= c) { prefix = want; setc = c; }
        else          { prefix = want | 1u; rem -= c; setc -= c; }
        bshift = bit;
        if (setc == rem) { bounded = true; break; }
    }

    if (lane == 0) cnt[wave] = 0;
    int* op = knn_out + (size_t)p * K_;
    const unsigned long long BE = bounded ? (((unsigned long long)prefix + 1ull) << bshift)
                                          : (unsigned long long)prefix;
#pragma unroll
    for (int j = 0; j < 32; ++j) {
        if ((unsigned long long)key[j] < BE) {
            int s = atomicAdd(&cnt[wave], 1);
            op[s] = j * 64 + lane;
        }
    }
    if (!bounded) {
        const unsigned V = prefix;
#pragma unroll
        for (int j = 0; j < 32; ++j) {
            if (rem > 0) {
                unsigned long long mask = __ballot(key[j] == V);
                int below = __popcll(mask & ((1ull << lane) - 1ull));
                if (key[j] == V && below < rem) {
                    int s = atomicAdd(&cnt[wave], 1);
                    op[s] = j * 64 + lane;
                }
                rem -= __popcll(mask);
            }
        }
    }
}

// ---------------------------------------------------------------------------
// Kernel 2: prepack W1/W2/W3/Ws into bf16 MFMA A-fragments, CHUNK-MAJOR:
// chunk c (16 KiB) = fragments [16c..16c+15] (= mt 0..15 of one kt).
//   fragment (c,mt): W[32kt + 8g + i][16mt + e]; c = L*8+kt, 24+kt (Ws).
// ---------------------------------------------------------------------------
__global__ __launch_bounds__(64) void wprep_kernel(const float* __restrict__ W1,
                                                   const float* __restrict__ W2,
                                                   const float* __restrict__ W3,
                                                   const float* __restrict__ Ws,
                                                   short* __restrict__ WF) {
    const int bi = blockIdx.x;          // 0..447
    const int lane = threadIdx.x;
    const int g = lane >> 4, e = lane & 15;
    const float* W;
    int mt, kt;
    if (bi < 384) {
        const int L = bi >> 7;
        const int t = bi & 127;         // t = kt*16 + mt
        kt = t >> 4; mt = t & 15;
        W = (L == 0) ? W1 : (L == 1) ? W2 : W3;
    } else {
        const int t = bi - 384;
        kt = t >> 4; mt = t & 15;
        W = Ws;
    }
    const int f = 16 * mt + e;
    unsigned v[4];
#pragma unroll
    for (int i2 = 0; i2 < 4; ++i2) {
        const int k = 32 * kt + 8 * g + 2 * i2;
        v[i2] = pack2(W[(size_t)k * E_ + f], W[(size_t)(k + 1) * E_ + f]);
    }
    uint4 u; u.x = v[0]; u.y = v[1]; u.z = v[2]; u.w = v[3];
    *reinterpret_cast<uint4*>(WF + ((size_t)bi * 64 + lane) * 8) = u;
}

// ---------------------------------------------------------------------------
// Kernel 3: fused edge-MLP, WAVE-PAIR mt-split. Waves (2q,2q+1) jointly
// process 2 points: each wave computes feature-half (8 mt) for BOTH points,
// so each W A-fragment read feeds 2 MFMAs (A-traffic halved). LN mean/var
// uses a cross-wave partial exchange (Xch) per layer. H is pair-shared.
// ---------------------------------------------------------------------------
#define WCHUNKS 28

__device__ __forceinline__ void stage_chunk(const short* __restrict__ WF,
                                            short* __restrict__ dst,
                                            int c, int wave, int lane) {
    const short* src = WF + ((size_t)(c << 4) << 9);    // fragment 16c, *512 shorts
#pragma unroll
    for (int i = 0; i < 4; ++i) {
        const int slot = (i << 8) + (wave << 6);        // wave-uniform slot base
        const short* gp = src + ((size_t)(slot + lane) << 3);
        short* lp = dst + ((size_t)slot << 3);
        __builtin_amdgcn_global_load_lds(
            (const __attribute__((address_space(1))) void*)gp,
            (__attribute__((address_space(3))) void*)lp, 16, 0, 0);
    }
}

__global__ __launch_bounds__(256, 2) void edgeconv_mfma(
    const float* __restrict__ x, const int* __restrict__ knn,
    const short* __restrict__ WF,
    const float* __restrict__ b1, const float* __restrict__ g1, const float* __restrict__ be1,
    const float* __restrict__ b2, const float* __restrict__ g2, const float* __restrict__ be2,
    const float* __restrict__ b3, const float* __restrict__ g3, const float* __restrict__ be3,
    const float* __restrict__ bs,
    float* __restrict__ out)
{
    __shared__ short Hl[2][2][4096];    // 32 KiB: [pair][point][16e x 256f bf16] swizzled
    __shared__ short Wbuf[2][8192];     // 32 KiB: double-buffered 16 KiB W chunks
    __shared__ short Hx[2][2][128];     // 1 KiB: bf16 x-row per pair/point
    __shared__ float4 Xch[2][2][16];    // 1 KiB: LN partial exchange (s0,q0,s1,q1)
    __shared__ float Pl[9 * 256];       // 9 KiB: b1,g1,be1,b2,g2,be2,b3,g3,be3
    const int tid  = threadIdx.x;
    const int wave = tid >> 6;
    const int lane = tid & 63;
    const int wq = wave & 1;            // parity within pair (feature-half owner)
    const int pr = wave >> 1;           // pair index
    const int e = lane & 15;
    const int g = lane >> 4;
    const int p = blockIdx.x * 4 + wave;   // own point (pair pr covers p0+2pr, +1)
    const int b = p >> 11;
    const int n = p & (N_ - 1);
    const unsigned swz = (unsigned)((e & 7) << 4);
    char* Hown = (char*)&Hl[pr][wq][0];
    char* Hp0  = (char*)&Hl[pr][0][0];
    char* Hp1  = (char*)&Hl[pr][1][0];
    char* XCo  = (char*)&Hx[pr][wq][0];
    const char* XC0 = (const char*)&Hx[pr][0][0];
    const char* XC1 = (const char*)&Hx[pr][1][0];

    // issue chunk-0 staging first so it flies under the H build
    stage_chunk(WF, &Wbuf[0][0], 0, wave, lane);

    // stage LN params once per block
    {
        const float* srcs[9] = {b1, g1, be1, b2, g2, be2, b3, g3, be3};
#pragma unroll
        for (int a = 0; a < 9; ++a) Pl[a * 256 + tid] = srcs[a][tid];
    }

    // ---- edge build (own point): H[e][0:128]=central, H[e][128:256]=nbr-central
    {
        const float4* xr = (const float4*)(x + ((size_t)b * N_ + n) * D_);
        const int nb = knn[(size_t)p * K_ + e];
        const float4* nr = (const float4*)(x + ((size_t)b * N_ + nb) * D_);
#pragma unroll
        for (int c2 = 0; c2 < 8; ++c2) {
            const float4 cv = xr[8 * g + c2];
            const float4 nv = nr[8 * g + c2];
            const int base = (e << 9) + (g << 6) + (c2 << 3);
            const uint2 cpk = make_uint2(pack2(cv.x, cv.y), pack2(cv.z, cv.w));
            *(uint2*)(Hown + (base ^ swz)) = cpk;
            *(uint2*)(Hown + ((base + 256) ^ swz)) =
                make_uint2(pack2(nv.x - cv.x, nv.y - cv.y), pack2(nv.z - cv.z, nv.w - cv.w));
            if (e == 0) *(uint2*)(XCo + (g << 6) + (c2 << 3)) = cpk;
        }
    }

    f32x4 acc0[8], acc1[8];             // [mtl] for point0 / point1 (64 AGPR)
    int pb = 0;
    const f32x4 z4 = {0.f, 0.f, 0.f, 0.f};

    for (int L = 0; L < 3; ++L) {
        const float* PlL = &Pl[L * 768];
#pragma unroll
        for (int mtl = 0; mtl < 8; ++mtl) { acc0[mtl] = z4; acc1[mtl] = z4; }

        for (int kt = 0; kt < 8; ++kt) {
            const int c = L * 8 + kt;
            asm volatile("s_waitcnt vmcnt(0)" ::: "memory");
            __syncthreads();
            if (c + 1 < WCHUNKS) stage_chunk(WF, &Wbuf[pb ^ 1][0], c + 1, wave, lane);
            const int offB = (int)((unsigned)((e << 9) + (kt << 6) + (g << 4)) ^ swz);
            const bf16x8 Bc0 = *(const bf16x8*)(Hp0 + offB);
            const bf16x8 Bc1 = *(const bf16x8*)(Hp1 + offB);
            const short* Wc = &Wbuf[pb][0];
            __builtin_amdgcn_s_setprio(1);
#pragma unroll
            for (int mtl = 0; mtl < 8; ++mtl) {
                const bf16x8 a = *(const bf16x8*)(Wc + ((((wq << 3) + mtl) << 6) + lane) * 8);
                acc0[mtl] = __builtin_amdgcn_mfma_f32_16x16x32_bf16(a, Bc0, acc0[mtl], 0, 0, 0);
                acc1[mtl] = __builtin_amdgcn_mfma_f32_16x16x32_bf16(a, Bc1, acc1[mtl], 0, 0, 0);
            }
            __builtin_amdgcn_s_setprio(0);
            pb ^= 1;
        }

        // ---- LN pass 1: bias + partial sums over this wave's 128 feats ----
        float s0 = 0.f, q0 = 0.f, s1 = 0.f, q1 = 0.f;
#pragma unroll
        for (int mtl = 0; mtl < 8; ++mtl) {
            const int mtg = (wq << 3) + mtl;
            const float4 bv = *(const float4*)(PlL + mtg * 16 + (g << 2));
            acc0[mtl][0] += bv.x; acc0[mtl][1] += bv.y; acc0[mtl][2] += bv.z; acc0[mtl][3] += bv.w;
            acc1[mtl][0] += bv.x; acc1[mtl][1] += bv.y; acc1[mtl][2] += bv.z; acc1[mtl][3] += bv.w;
            s0 += (acc0[mtl][0] + acc0[mtl][1]) + (acc0[mtl][2] + acc0[mtl][3]);
            q0 = fmaf(acc0[mtl][0], acc0[mtl][0], q0); q0 = fmaf(acc0[mtl][1], acc0[mtl][1], q0);
            q0 = fmaf(acc0[mtl][2], acc0[mtl][2], q0); q0 = fmaf(acc0[mtl][3], acc0[mtl][3], q0);
            s1 += (acc1[mtl][0] + acc1[mtl][1]) + (acc1[mtl][2] + acc1[mtl][3]);
            q1 = fmaf(acc1[mtl][0], acc1[mtl][0], q1); q1 = fmaf(acc1[mtl][1], acc1[mtl][1], q1);
            q1 = fmaf(acc1[mtl][2], acc1[mtl][2], q1); q1 = fmaf(acc1[mtl][3], acc1[mtl][3], q1);
        }
        s0 += __shfl_xor(s0, 16, 64); s0 += __shfl_xor(s0, 32, 64);
        q0 += __shfl_xor(q0, 16, 64); q0 += __shfl_xor(q0, 32, 64);
        s1 += __shfl_xor(s1, 16, 64); s1 += __shfl_xor(s1, 32, 64);
        q1 += __shfl_xor(q1, 16, 64); q1 += __shfl_xor(q1, 32, 64);
        if (lane < 16) Xch[pr][wq][e] = make_float4(s0, q0, s1, q1);
        __syncthreads();
        const float4 oX = Xch[pr][wq ^ 1][e];
        const float mu0 = (s0 + oX.x) * (1.0f / 256.0f);
        const float var0 = fmaf(-mu0, mu0, (q0 + oX.y) * (1.0f / 256.0f));
        const float rstd0 = rsqrtf(var0 + LN_EPS);
        const float mu1 = (s1 + oX.z) * (1.0f / 256.0f);
        const float var1 = fmaf(-mu1, mu1, (q1 + oX.w) * (1.0f / 256.0f));
        const float rstd1 = rsqrtf(var1 + LN_EPS);

        // ---- LN pass 2 + GELU ----
#pragma unroll
        for (int mtl = 0; mtl < 8; ++mtl) {
            const int mtg = (wq << 3) + mtl;
            const float4 gv  = *(const float4*)(PlL + 256 + mtg * 16 + (g << 2));
            const float4 bev = *(const float4*)(PlL + 512 + mtg * 16 + (g << 2));
            const float A00 = rstd0 * gv.x, A01 = rstd0 * gv.y, A02 = rstd0 * gv.z, A03 = rstd0 * gv.w;
            const float r00 = gelu_fast(fmaf(acc0[mtl][0], A00, fmaf(-mu0, A00, bev.x)));
            const float r01 = gelu_fast(fmaf(acc0[mtl][1], A01, fmaf(-mu0, A01, bev.y)));
            const float r02 = gelu_fast(fmaf(acc0[mtl][2], A02, fmaf(-mu0, A02, bev.z)));
            const float r03 = gelu_fast(fmaf(acc0[mtl][3], A03, fmaf(-mu0, A03, bev.w)));
            const float A10 = rstd1 * gv.x, A11 = rstd1 * gv.y, A12 = rstd1 * gv.z, A13 = rstd1 * gv.w;
            const float r10 = gelu_fast(fmaf(acc1[mtl][0], A10, fmaf(-mu1, A10, bev.x)));
            const float r11 = gelu_fast(fmaf(acc1[mtl][1], A11, fmaf(-mu1, A11, bev.y)));
            const float r12 = gelu_fast(fmaf(acc1[mtl][2], A12, fmaf(-mu1, A12, bev.z)));
            const float r13 = gelu_fast(fmaf(acc1[mtl][3], A13, fmaf(-mu1, A13, bev.w)));
            if (L < 2) {
                const int wb = (int)((unsigned)((e << 9) + (mtg << 5) + (g << 3)) ^ swz);
                *(uint2*)(Hp0 + wb) = make_uint2(pack2(r00, r01), pack2(r02, r03));
                *(uint2*)(Hp1 + wb) = make_uint2(pack2(r10, r11), pack2(r12, r13));
            } else {
                acc0[mtl][0] = r00; acc0[mtl][1] = r01; acc0[mtl][2] = r02; acc0[mtl][3] = r03;
                acc1[mtl][0] = r10; acc1[mtl][1] = r11; acc1[mtl][2] = r12; acc1[mtl][3] = r13;
            }
        }
        // next phase's __syncthreads makes H writes visible before B reads
    }

    // ---- max over 16 edges (DPP row reduce) + bounce to Sb (Hl is dead) ----
#pragma unroll
    for (int mtl = 0; mtl < 8; ++mtl) {
#pragma unroll
        for (int i = 0; i < 4; ++i) {
            acc0[mtl][i] = dpp_rowmax16(acc0[mtl][i]);
            acc1[mtl][i] = dpp_rowmax16(acc1[mtl][i]);
        }
    }
    float* Sb0 = (float*)Hp0;
    float* Sb1 = (float*)Hp1;
#pragma unroll
    for (int mtl = 0; mtl < 8; ++mtl) {
        if (e == mtl) {
            const int fo = (((wq << 3) + mtl) << 4) + (g << 2);
            *(float4*)(Sb0 + fo) = *(const float4*)&acc0[mtl];
            *(float4*)(Sb1 + fo) = *(const float4*)&acc1[mtl];
        }
    }

    // ---- shortcut x @ Ws via MFMA (chunks 24..27), REUSING acc ----
#pragma unroll
    for (int mtl = 0; mtl < 8; ++mtl) { acc0[mtl] = z4; acc1[mtl] = z4; }
    for (int kt = 0; kt < 4; ++kt) {
        const int c = 24 + kt;
        asm volatile("s_waitcnt vmcnt(0)" ::: "memory");
        __syncthreads();
        if (c + 1 < WCHUNKS) stage_chunk(WF, &Wbuf[pb ^ 1][0], c + 1, wave, lane);
        const bf16x8 bx0 = *(const bf16x8*)(XC0 + (kt << 6) + (g << 4));
        const bf16x8 bx1 = *(const bf16x8*)(XC1 + (kt << 6) + (g << 4));
        const short* Wc = &Wbuf[pb][0];
        __builtin_amdgcn_s_setprio(1);
#pragma unroll
        for (int mtl = 0; mtl < 8; ++mtl) {
            const bf16x8 a = *(const bf16x8*)(Wc + ((((wq << 3) + mtl) << 6) + lane) * 8);
            acc0[mtl] = __builtin_amdgcn_mfma_f32_16x16x32_bf16(a, bx0, acc0[mtl], 0, 0, 0);
            acc1[mtl] = __builtin_amdgcn_mfma_f32_16x16x32_bf16(a, bx1, acc1[mtl], 0, 0, 0);
        }
        __builtin_amdgcn_s_setprio(0);
        pb ^= 1;
    }
    // shortcut cols identical (broadcast B) -> bounce directly
#pragma unroll
    for (int mtl = 0; mtl < 8; ++mtl) {
        if (e == mtl) {
            const int fo = (((wq << 3) + mtl) << 4) + (g << 2);
            *(float4*)(Sb0 + 256 + fo) = *(const float4*)&acc0[mtl];
            *(float4*)(Sb1 + 256 + fo) = *(const float4*)&acc1[mtl];
        }
    }
    __syncthreads();

    // ---- final epilogue: own point, feats f0..f0+3 ----
    const int f0 = 16 * e + (g << 2);
    const float* SbO = wq ? Sb1 : Sb0;
    const float4 agg = *(const float4*)(SbO + f0);
    const float4 ssc = *(const float4*)(SbO + 256 + f0);
    const float4 bsv = *(const float4*)(bs + f0);
    float4 o;
    o.x = gelu_fast(agg.x + ssc.x + bsv.x);
    o.y = gelu_fast(agg.y + ssc.y + bsv.y);
    o.z = gelu_fast(agg.z + ssc.z + bsv.z);
    o.w = gelu_fast(agg.w + ssc.w + bsv.w);
    *(float4*)(out + (size_t)p * E_ + f0) = o;
}

extern "C" void kernel_launch(void* const* d_in, const int* in_sizes, int n_in,
                              void* d_out, int out_size, void* d_ws, size_t ws_size,
                              hipStream_t stream) {
    const float* x      = (const float*)d_in[0];
    const float* coords = (const float*)d_in[1];
    const float* W1  = (const float*)d_in[2];
    const float* b1  = (const float*)d_in[3];
    const float* g1  = (const float*)d_in[4];
    const float* be1 = (const float*)d_in[5];
    const float* W2  = (const float*)d_in[6];
    const float* b2  = (const float*)d_in[7];
    const float* g2  = (const float*)d_in[8];
    const float* be2 = (const float*)d_in[9];
    const float* W3  = (const float*)d_in[10];
    const float* b3  = (const float*)d_in[11];
    const float* g3  = (const float*)d_in[12];
    const float* be3 = (const float*)d_in[13];
    const float* Ws  = (const float*)d_in[14];
    const float* bs  = (const float*)d_in[15];
    float* out = (float*)d_out;

    int*   knn = (int*)d_ws;                          // 1 MiB
    short* WF  = (short*)((char*)d_ws + (1 << 20));   // 448 KiB bf16 fragments

    wprep_kernel<<<448, 64, 0, stream>>>(W1, W2, W3, Ws, WF);
    knn_select_kernel<<<B_ * (N_ / 8), 512, 0, stream>>>(coords, knn);
    edgeconv_mfma<<<(B_ * N_) / 4, 256, 0, stream>>>(
        x, knn, WF, b1, g1, be1, b2, g2, be2, b3, g3, be3, bs, out);
}

// Round 9
// 333.555 us; speedup vs baseline: 2.0531x; 1.1652x over previous
//
#include <hip/hip_runtime.h>
#include <hip/hip_bf16.h>
#include <math.h>

#define B_ 8
#define N_ 2048
#define D_ 128
#define E_ 256
#define K_ 16
#define LN_EPS 1e-5f

typedef short bf16x8 __attribute__((ext_vector_type(8)));
typedef float f32x4 __attribute__((ext_vector_type(4)));
typedef float f32x2 __attribute__((ext_vector_type(2)));

// ---------------------------------------------------------------------------
// Reference-matching f32 distance (expanded form, no FMA contraction).
// ---------------------------------------------------------------------------
__device__ __forceinline__ float sq3_ref(float x, float y, float z) {
#pragma clang fp contract(off)
    float s = x * x + y * y;
    s = s + z * z;
    return s;
}
__device__ __forceinline__ float d2_ref(float qx, float qy, float qz, float sqq,
                                        float mx, float my, float mz, float sqm) {
#pragma clang fp contract(off)
    float dot = mx * qx + my * qy;
    dot = dot + mz * qz;
    float t1 = sqq + sqm;
    float t2 = 2.0f * dot;
    float d2 = t1 - t2;
    return d2 > 0.0f ? d2 : 0.0f;
}

// pack two f32 -> bf16x2 dword (compiler fuses to v_cvt_pk_bf16_f32)
__device__ __forceinline__ unsigned pack2(float a, float b) {
    union { __hip_bfloat162 h2; unsigned u; } cv;
    cv.h2 = __float22bfloat162_rn(float2{a, b});
    return cv.u;
}

// tanh-form GELU on a PAIR via sigmoid identity, written in f32x2 vector form
// so LLVM can emit v_pk_{mul,fma,add}_f32. gelu(v) = v / (1 + exp2(-2u*log2e)),
// u = 0.7978845608 v (1 + 0.044715 v^2); const = 2*0.7978845608*log2e.
__device__ __forceinline__ f32x2 gelu2(f32x2 v) {
    const f32x2 w = v * v;
    f32x2 inner = w * 0.044715f;
    inner.x += 1.0f; inner.y += 1.0f;
    const f32x2 ue = (v * -2.3022083f) * inner;      // -2u*log2e
    f32x2 t;
    t.x = __builtin_amdgcn_exp2f(ue.x);
    t.y = __builtin_amdgcn_exp2f(ue.y);
    f32x2 den = t;
    den.x += 1.0f; den.y += 1.0f;
    f32x2 r;
    r.x = __builtin_amdgcn_rcpf(den.x);
    r.y = __builtin_amdgcn_rcpf(den.y);
    return v * r;
}

// max over the 16 contiguous lanes of a DPP row (e = lane&15), VALU-only.
__device__ __forceinline__ float dpp_rowmax16(float v) {
    int x = __float_as_int(v);
    v = fmaxf(v, __int_as_float(__builtin_amdgcn_mov_dpp(x, 0xB1, 0xF, 0xF, true)));
    x = __float_as_int(v);
    v = fmaxf(v, __int_as_float(__builtin_amdgcn_mov_dpp(x, 0x4E, 0xF, 0xF, true)));
    x = __float_as_int(v);
    v = fmaxf(v, __int_as_float(__builtin_amdgcn_mov_dpp(x, 0x141, 0xF, 0xF, true)));
    x = __float_as_int(v);
    v = fmaxf(v, __int_as_float(__builtin_amdgcn_mov_dpp(x, 0x140, 0xF, 0xF, true)));
    return v;
}

// ---------------------------------------------------------------------------
// Kernel 1: kNN top-16 via branch-free radix select (one wave per query).
// ---------------------------------------------------------------------------
__global__ __launch_bounds__(512) void knn_select_kernel(const float* __restrict__ coords,
                                                         int* __restrict__ knn_out) {
    __shared__ float lc[3][N_];
    __shared__ float lsq[N_];
    __shared__ int cnt[8];
    const int wave = threadIdx.x >> 6;
    const int lane = threadIdx.x & 63;
    const int p = blockIdx.x * 8 + wave;
    const int b = p >> 11;
    const int n0 = p & (N_ - 1);
    const float* cb = coords + (size_t)b * N_ * 3;
    for (int i = threadIdx.x; i < N_ * 3; i += 512) {
        int n = i / 3, c = i - 3 * n;
        lc[c][n] = cb[i];
    }
    __syncthreads();
    for (int n = threadIdx.x; n < N_; n += 512) lsq[n] = sq3_ref(lc[0][n], lc[1][n], lc[2][n]);
    __syncthreads();

    const float qx = lc[0][n0], qy = lc[1][n0], qz = lc[2][n0], sqq = lsq[n0];
    unsigned key[32];
#pragma unroll
    for (int j = 0; j < 32; ++j) {
        const int m = j * 64 + lane;
        key[j] = __float_as_uint(d2_ref(qx, qy, qz, sqq, lc[0][m], lc[1][m], lc[2][m], lsq[m]));
    }

    unsigned prefix = 0;
    int rem = K_, setc = N_, bshift = 0;
    bool bounded = false;
    for (int bit = 31; bit >= 0; --bit) {
        const unsigned want = prefix << 1;
        int c = 0;
#pragma unroll
        for (int j = 0; j < 32; ++j) c += ((key[j] >> bit) == want) ? 1 : 0;
        for (int off = 1; off < 64; off <<= 1) c += __shfl_xor(c, off, 64);
        if (rem <= c) { prefix = want; setc = c; }
        else          { prefix = want | 1u; rem -= c; setc -= c; }
        bshift = bit;
        if (setc == rem) { bounded = true; break; }
    }

    if (lane == 0) cnt[wave] = 0;
    int* op = knn_out + (size_t)p * K_;
    const unsigned long long BE = bounded ? (((unsigned long long)prefix + 1ull) << bshift)
                                          : (unsigned long long)prefix;
#pragma unroll
    for (int j = 0; j < 32; ++j) {
        if ((unsigned long long)key[j] < BE) {
            int s = atomicAdd(&cnt[wave], 1);
            op[s] = j * 64 + lane;
        }
    }
    if (!bounded) {
        const unsigned V = prefix;
#pragma unroll
        for (int j = 0; j < 32; ++j) {
            if (rem > 0) {
                unsigned long long mask = __ballot(key[j] == V);
                int below = __popcll(mask & ((1ull << lane) - 1ull));
                if (key[j] == V && below < rem) {
                    int s = atomicAdd(&cnt[wave], 1);
                    op[s] = j * 64 + lane;
                }
                rem -= __popcll(mask);
            }
        }
    }
}

// ---------------------------------------------------------------------------
// Kernel 2: prepack W1/W2/W3/Ws into bf16 MFMA A-fragments, CHUNK-MAJOR:
// chunk c (16 KiB) = fragments [16c..16c+15] (= mt 0..15 of one kt).
//   fragment (c,mt): W[32kt + 8g + i][16mt + e]; c = L*8+kt, 24+kt (Ws).
// ---------------------------------------------------------------------------
__global__ __launch_bounds__(64) void wprep_kernel(const float* __restrict__ W1,
                                                   const float* __restrict__ W2,
                                                   const float* __restrict__ W3,
                                                   const float* __restrict__ Ws,
                                                   short* __restrict__ WF) {
    const int bi = blockIdx.x;          // 0..447
    const int lane = threadIdx.x;
    const int g = lane >> 4, e = lane & 15;
    const float* W;
    int mt, kt;
    if (bi < 384) {
        const int L = bi >> 7;
        const int t = bi & 127;         // t = kt*16 + mt
        kt = t >> 4; mt = t & 15;
        W = (L == 0) ? W1 : (L == 1) ? W2 : W3;
    } else {
        const int t = bi - 384;
        kt = t >> 4; mt = t & 15;
        W = Ws;
    }
    const int f = 16 * mt + e;
    unsigned v[4];
#pragma unroll
    for (int i2 = 0; i2 < 4; ++i2) {
        const int k = 32 * kt + 8 * g + 2 * i2;
        v[i2] = pack2(W[(size_t)k * E_ + f], W[(size_t)(k + 1) * E_ + f]);
    }
    uint4 u; u.x = v[0]; u.y = v[1]; u.z = v[2]; u.w = v[3];
    *reinterpret_cast<uint4*>(WF + ((size_t)bi * 64 + lane) * 8) = u;
}

// ---------------------------------------------------------------------------
// Kernel 3: fused edge-MLP, WAVE-PAIR mt-split (R8 structure). LN/GELU
// elementwise phases written in f32x2 form to coax v_pk_*_f32.
// ---------------------------------------------------------------------------
#define WCHUNKS 28

__device__ __forceinline__ void stage_chunk(const short* __restrict__ WF,
                                            short* __restrict__ dst,
                                            int c, int wave, int lane) {
    const short* src = WF + ((size_t)(c << 4) << 9);    // fragment 16c, *512 shorts
#pragma unroll
    for (int i = 0; i < 4; ++i) {
        const int slot = (i << 8) + (wave << 6);        // wave-uniform slot base
        const short* gp = src + ((size_t)(slot + lane) << 3);
        short* lp = dst + ((size_t)slot << 3);
        __builtin_amdgcn_global_load_lds(
            (const __attribute__((address_space(1))) void*)gp,
            (__attribute__((address_space(3))) void*)lp, 16, 0, 0);
    }
}

__global__ __launch_bounds__(256, 2) void edgeconv_mfma(
    const float* __restrict__ x, const int* __restrict__ knn,
    const short* __restrict__ WF,
    const float* __restrict__ b1, const float* __restrict__ g1, const float* __restrict__ be1,
    const float* __restrict__ b2, const float* __restrict__ g2, const float* __restrict__ be2,
    const float* __restrict__ b3, const float* __restrict__ g3, const float* __restrict__ be3,
    const float* __restrict__ bs,
    float* __restrict__ out)
{
    __shared__ short Hl[2][2][4096];    // 32 KiB: [pair][point][16e x 256f bf16] swizzled
    __shared__ short Wbuf[2][8192];     // 32 KiB: double-buffered 16 KiB W chunks
    __shared__ short Hx[2][2][128];     // 1 KiB: bf16 x-row per pair/point
    __shared__ float4 Xch[2][2][16];    // 1 KiB: LN partial exchange (s0,q0,s1,q1)
    __shared__ float Pl[9 * 256];       // 9 KiB: b1,g1,be1,b2,g2,be2,b3,g3,be3
    const int tid  = threadIdx.x;
    const int wave = tid >> 6;
    const int lane = tid & 63;
    const int wq = wave & 1;            // parity within pair (feature-half owner)
    const int pr = wave >> 1;           // pair index
    const int e = lane & 15;
    const int g = lane >> 4;
    const int p = blockIdx.x * 4 + wave;   // own point
    const int b = p >> 11;
    const int n = p & (N_ - 1);
    const unsigned swz = (unsigned)((e & 7) << 4);
    char* Hown = (char*)&Hl[pr][wq][0];
    char* Hp0  = (char*)&Hl[pr][0][0];
    char* Hp1  = (char*)&Hl[pr][1][0];
    char* XCo  = (char*)&Hx[pr][wq][0];
    const char* XC0 = (const char*)&Hx[pr][0][0];
    const char* XC1 = (const char*)&Hx[pr][1][0];

    // issue chunk-0 staging first so it flies under the H build
    stage_chunk(WF, &Wbuf[0][0], 0, wave, lane);

    // stage LN params once per block
    {
        const float* srcs[9] = {b1, g1, be1, b2, g2, be2, b3, g3, be3};
#pragma unroll
        for (int a = 0; a < 9; ++a) Pl[a * 256 + tid] = srcs[a][tid];
    }

    // ---- edge build (own point): H[e][0:128]=central, H[e][128:256]=nbr-central
    {
        const float4* xr = (const float4*)(x + ((size_t)b * N_ + n) * D_);
        const int nb = knn[(size_t)p * K_ + e];
        const float4* nr = (const float4*)(x + ((size_t)b * N_ + nb) * D_);
#pragma unroll
        for (int c2 = 0; c2 < 8; ++c2) {
            const float4 cv = xr[8 * g + c2];
            const float4 nv = nr[8 * g + c2];
            const int base = (e << 9) + (g << 6) + (c2 << 3);
            const uint2 cpk = make_uint2(pack2(cv.x, cv.y), pack2(cv.z, cv.w));
            *(uint2*)(Hown + (base ^ swz)) = cpk;
            *(uint2*)(Hown + ((base + 256) ^ swz)) =
                make_uint2(pack2(nv.x - cv.x, nv.y - cv.y), pack2(nv.z - cv.z, nv.w - cv.w));
            if (e == 0) *(uint2*)(XCo + (g << 6) + (c2 << 3)) = cpk;
        }
    }

    f32x4 acc0[8], acc1[8];             // [mtl] for point0 / point1
    int pb = 0;
    const f32x4 z4 = {0.f, 0.f, 0.f, 0.f};

    for (int L = 0; L < 3; ++L) {
        const float* PlL = &Pl[L * 768];
#pragma unroll
        for (int mtl = 0; mtl < 8; ++mtl) { acc0[mtl] = z4; acc1[mtl] = z4; }

        for (int kt = 0; kt < 8; ++kt) {
            const int c = L * 8 + kt;
            asm volatile("s_waitcnt vmcnt(0)" ::: "memory");
            __syncthreads();
            if (c + 1 < WCHUNKS) stage_chunk(WF, &Wbuf[pb ^ 1][0], c + 1, wave, lane);
            const int offB = (int)((unsigned)((e << 9) + (kt << 6) + (g << 4)) ^ swz);
            const bf16x8 Bc0 = *(const bf16x8*)(Hp0 + offB);
            const bf16x8 Bc1 = *(const bf16x8*)(Hp1 + offB);
            const short* Wc = &Wbuf[pb][0];
            __builtin_amdgcn_s_setprio(1);
#pragma unroll
            for (int mtl = 0; mtl < 8; ++mtl) {
                const bf16x8 a = *(const bf16x8*)(Wc + ((((wq << 3) + mtl) << 6) + lane) * 8);
                acc0[mtl] = __builtin_amdgcn_mfma_f32_16x16x32_bf16(a, Bc0, acc0[mtl], 0, 0, 0);
                acc1[mtl] = __builtin_amdgcn_mfma_f32_16x16x32_bf16(a, Bc1, acc1[mtl], 0, 0, 0);
            }
            __builtin_amdgcn_s_setprio(0);
            pb ^= 1;
        }

        // ---- LN pass 1: bias + partial sums (f32x2 / pk form) ----
        f32x2 s2_0 = {0.f, 0.f}, q2_0 = {0.f, 0.f};
        f32x2 s2_1 = {0.f, 0.f}, q2_1 = {0.f, 0.f};
#pragma unroll
        for (int mtl = 0; mtl < 8; ++mtl) {
            const int mtg = (wq << 3) + mtl;
            const float4 bv = *(const float4*)(PlL + mtg * 16 + (g << 2));
            const f32x2 blo = {bv.x, bv.y}, bhi = {bv.z, bv.w};
            f32x2 a0lo = {acc0[mtl][0], acc0[mtl][1]};
            f32x2 a0hi = {acc0[mtl][2], acc0[mtl][3]};
            f32x2 a1lo = {acc1[mtl][0], acc1[mtl][1]};
            f32x2 a1hi = {acc1[mtl][2], acc1[mtl][3]};
            a0lo = a0lo + blo; a0hi = a0hi + bhi;
            a1lo = a1lo + blo; a1hi = a1hi + bhi;
            s2_0 = s2_0 + a0lo; s2_0 = s2_0 + a0hi;
            q2_0 = q2_0 + a0lo * a0lo; q2_0 = q2_0 + a0hi * a0hi;
            s2_1 = s2_1 + a1lo; s2_1 = s2_1 + a1hi;
            q2_1 = q2_1 + a1lo * a1lo; q2_1 = q2_1 + a1hi * a1hi;
            acc0[mtl][0] = a0lo.x; acc0[mtl][1] = a0lo.y;
            acc0[mtl][2] = a0hi.x; acc0[mtl][3] = a0hi.y;
            acc1[mtl][0] = a1lo.x; acc1[mtl][1] = a1lo.y;
            acc1[mtl][2] = a1hi.x; acc1[mtl][3] = a1hi.y;
        }
        float s0 = s2_0.x + s2_0.y, q0 = q2_0.x + q2_0.y;
        float s1 = s2_1.x + s2_1.y, q1 = q2_1.x + q2_1.y;
        s0 += __shfl_xor(s0, 16, 64); s0 += __shfl_xor(s0, 32, 64);
        q0 += __shfl_xor(q0, 16, 64); q0 += __shfl_xor(q0, 32, 64);
        s1 += __shfl_xor(s1, 16, 64); s1 += __shfl_xor(s1, 32, 64);
        q1 += __shfl_xor(q1, 16, 64); q1 += __shfl_xor(q1, 32, 64);
        if (lane < 16) Xch[pr][wq][e] = make_float4(s0, q0, s1, q1);
        __syncthreads();
        const float4 oX = Xch[pr][wq ^ 1][e];
        const float mu0 = (s0 + oX.x) * (1.0f / 256.0f);
        const float var0 = fmaf(-mu0, mu0, (q0 + oX.y) * (1.0f / 256.0f));
        const float rstd0 = rsqrtf(var0 + LN_EPS);
        const float mu1 = (s1 + oX.z) * (1.0f / 256.0f);
        const float var1 = fmaf(-mu1, mu1, (q1 + oX.w) * (1.0f / 256.0f));
        const float rstd1 = rsqrtf(var1 + LN_EPS);

        // ---- LN pass 2 + GELU (f32x2 / pk form) ----
#pragma unroll
        for (int mtl = 0; mtl < 8; ++mtl) {
            const int mtg = (wq << 3) + mtl;
            const float4 gv  = *(const float4*)(PlL + 256 + mtg * 16 + (g << 2));
            const float4 bev = *(const float4*)(PlL + 512 + mtg * 16 + (g << 2));
            const f32x2 glo = {gv.x, gv.y}, ghi = {gv.z, gv.w};
            const f32x2 belo = {bev.x, bev.y}, behi = {bev.z, bev.w};
            // point 0
            const f32x2 A0lo = glo * rstd0, A0hi = ghi * rstd0;
            const f32x2 C0lo = A0lo * (-mu0) + belo, C0hi = A0hi * (-mu0) + behi;
            const f32x2 v0lo = {acc0[mtl][0], acc0[mtl][1]};
            const f32x2 v0hi = {acc0[mtl][2], acc0[mtl][3]};
            const f32x2 r0lo = gelu2(v0lo * A0lo + C0lo);
            const f32x2 r0hi = gelu2(v0hi * A0hi + C0hi);
            // point 1
            const f32x2 A1lo = glo * rstd1, A1hi = ghi * rstd1;
            const f32x2 C1lo = A1lo * (-mu1) + belo, C1hi = A1hi * (-mu1) + behi;
            const f32x2 v1lo = {acc1[mtl][0], acc1[mtl][1]};
            const f32x2 v1hi = {acc1[mtl][2], acc1[mtl][3]};
            const f32x2 r1lo = gelu2(v1lo * A1lo + C1lo);
            const f32x2 r1hi = gelu2(v1hi * A1hi + C1hi);
            if (L < 2) {
                const int wb = (int)((unsigned)((e << 9) + (mtg << 5) + (g << 3)) ^ swz);
                *(uint2*)(Hp0 + wb) = make_uint2(pack2(r0lo.x, r0lo.y), pack2(r0hi.x, r0hi.y));
                *(uint2*)(Hp1 + wb) = make_uint2(pack2(r1lo.x, r1lo.y), pack2(r1hi.x, r1hi.y));
            } else {
                acc0[mtl][0] = r0lo.x; acc0[mtl][1] = r0lo.y;
                acc0[mtl][2] = r0hi.x; acc0[mtl][3] = r0hi.y;
                acc1[mtl][0] = r1lo.x; acc1[mtl][1] = r1lo.y;
                acc1[mtl][2] = r1hi.x; acc1[mtl][3] = r1hi.y;
            }
        }
        // next phase's __syncthreads makes H writes visible before B reads
    }

    // ---- max over 16 edges (DPP row reduce) + bounce to Sb (Hl is dead) ----
#pragma unroll
    for (int mtl = 0; mtl < 8; ++mtl) {
#pragma unroll
        for (int i = 0; i < 4; ++i) {
            acc0[mtl][i] = dpp_rowmax16(acc0[mtl][i]);
            acc1[mtl][i] = dpp_rowmax16(acc1[mtl][i]);
        }
    }
    float* Sb0 = (float*)Hp0;
    float* Sb1 = (float*)Hp1;
#pragma unroll
    for (int mtl = 0; mtl < 8; ++mtl) {
        if (e == mtl) {
            const int fo = (((wq << 3) + mtl) << 4) + (g << 2);
            *(float4*)(Sb0 + fo) = *(const float4*)&acc0[mtl];
            *(float4*)(Sb1 + fo) = *(const float4*)&acc1[mtl];
        }
    }

    // ---- shortcut x @ Ws via MFMA (chunks 24..27), REUSING acc ----
#pragma unroll
    for (int mtl = 0; mtl < 8; ++mtl) { acc0[mtl] = z4; acc1[mtl] = z4; }
    for (int kt = 0; kt < 4; ++kt) {
        const int c = 24 + kt;
        asm volatile("s_waitcnt vmcnt(0)" ::: "memory");
        __syncthreads();
        if (c + 1 < WCHUNKS) stage_chunk(WF, &Wbuf[pb ^ 1][0], c + 1, wave, lane);
        const bf16x8 bx0 = *(const bf16x8*)(XC0 + (kt << 6) + (g << 4));
        const bf16x8 bx1 = *(const bf16x8*)(XC1 + (kt << 6) + (g << 4));
        const short* Wc = &Wbuf[pb][0];
        __builtin_amdgcn_s_setprio(1);
#pragma unroll
        for (int mtl = 0; mtl < 8; ++mtl) {
            const bf16x8 a = *(const bf16x8*)(Wc + ((((wq << 3) + mtl) << 6) + lane) * 8);
            acc0[mtl] = __builtin_amdgcn_mfma_f32_16x16x32_bf16(a, bx0, acc0[mtl], 0, 0, 0);
            acc1[mtl] = __builtin_amdgcn_mfma_f32_16x16x32_bf16(a, bx1, acc1[mtl], 0, 0, 0);
        }
        __builtin_amdgcn_s_setprio(0);
        pb ^= 1;
    }
    // shortcut cols identical (broadcast B) -> bounce directly
#pragma unroll
    for (int mtl = 0; mtl < 8; ++mtl) {
        if (e == mtl) {
            const int fo = (((wq << 3) + mtl) << 4) + (g << 2);
            *(float4*)(Sb0 + 256 + fo) = *(const float4*)&acc0[mtl];
            *(float4*)(Sb1 + 256 + fo) = *(const float4*)&acc1[mtl];
        }
    }
    __syncthreads();

    // ---- final epilogue: own point, feats f0..f0+3 ----
    const int f0 = 16 * e + (g << 2);
    const float* SbO = wq ? Sb1 : Sb0;
    const float4 agg = *(const float4*)(SbO + f0);
    const float4 ssc = *(const float4*)(SbO + 256 + f0);
    const float4 bsv = *(const float4*)(bs + f0);
    f32x2 elo = {agg.x + ssc.x, agg.y + ssc.y};
    f32x2 ehi = {agg.z + ssc.z, agg.w + ssc.w};
    const f32x2 blo = {bsv.x, bsv.y}, bhi = {bsv.z, bsv.w};
    const f32x2 olo = gelu2(elo + blo);
    const f32x2 ohi = gelu2(ehi + bhi);
    float4 o;
    o.x = olo.x; o.y = olo.y; o.z = ohi.x; o.w = ohi.y;
    *(float4*)(out + (size_t)p * E_ + f0) = o;
}

extern "C" void kernel_launch(void* const* d_in, const int* in_sizes, int n_in,
                              void* d_out, int out_size, void* d_ws, size_t ws_size,
                              hipStream_t stream) {
    const float* x      = (const float*)d_in[0];
    const float* coords = (const float*)d_in[1];
    const float* W1  = (const float*)d_in[2];
    const float* b1  = (const float*)d_in[3];
    const float* g1  = (const float*)d_in[4];
    const float* be1 = (const float*)d_in[5];
    const float* W2  = (const float*)d_in[6];
    const float* b2  = (const float*)d_in[7];
    const float* g2  = (const float*)d_in[8];
    const float* be2 = (const float*)d_in[9];
    const float* W3  = (const float*)d_in[10];
    const float* b3  = (const float*)d_in[11];
    const float* g3  = (const float*)d_in[12];
    const float* be3 = (const float*)d_in[13];
    const float* Ws  = (const float*)d_in[14];
    const float* bs  = (const float*)d_in[15];
    float* out = (float*)d_out;

    int*   knn = (int*)d_ws;                          // 1 MiB
    short* WF  = (short*)((char*)d_ws + (1 << 20));   // 448 KiB bf16 fragments

    wprep_kernel<<<448, 64, 0, stream>>>(W1, W2, W3, Ws, WF);
    knn_select_kernel<<<B_ * (N_ / 8), 512, 0, stream>>>(coords, knn);
    edgeconv_mfma<<<(B_ * N_) / 4, 256, 0, stream>>>(
        x, knn, WF, b1, g1, be1, b2, g2, be2, b3, g3, be3, bs, out);
}

// Round 10
// 330.214 us; speedup vs baseline: 2.0739x; 1.0101x over previous
//
#include <hip/hip_runtime.h>
#include <hip/hip_bf16.h>
#include <math.h>

#define B_ 8
#define N_ 2048
#define D_ 128
#define E_ 256
#define K_ 16
#define LN_EPS 1e-5f

typedef short bf16x8 __attribute__((ext_vector_type(8)));
typedef float f32x4 __attribute__((ext_vector_type(4)));
typedef float f32x2 __attribute__((ext_vector_type(2)));

// ---------------------------------------------------------------------------
// Reference-matching f32 distance (expanded form, no FMA contraction).
// ---------------------------------------------------------------------------
__device__ __forceinline__ float sq3_ref(float x, float y, float z) {
#pragma clang fp contract(off)
    float s = x * x + y * y;
    s = s + z * z;
    return s;
}
__device__ __forceinline__ float d2_ref(float qx, float qy, float qz, float sqq,
                                        float mx, float my, float mz, float sqm) {
#pragma clang fp contract(off)
    float dot = mx * qx + my * qy;
    dot = dot + mz * qz;
    float t1 = sqq + sqm;
    float t2 = 2.0f * dot;
    float d2 = t1 - t2;
    return d2 > 0.0f ? d2 : 0.0f;
}

// pack two f32 -> bf16x2 dword (compiler fuses to v_cvt_pk_bf16_f32)
__device__ __forceinline__ unsigned pack2(float a, float b) {
    union { __hip_bfloat162 h2; unsigned u; } cv;
    cv.h2 = __float22bfloat162_rn(float2{a, b});
    return cv.u;
}

// tanh-form GELU pair via sigmoid identity, f32x2 vector form (v_pk_* ops)
__device__ __forceinline__ f32x2 gelu2(f32x2 v) {
    const f32x2 w = v * v;
    f32x2 inner = w * 0.044715f;
    inner.x += 1.0f; inner.y += 1.0f;
    const f32x2 ue = (v * -2.3022083f) * inner;      // -2u*log2e
    f32x2 t;
    t.x = __builtin_amdgcn_exp2f(ue.x);
    t.y = __builtin_amdgcn_exp2f(ue.y);
    f32x2 den = t;
    den.x += 1.0f; den.y += 1.0f;
    f32x2 r;
    r.x = __builtin_amdgcn_rcpf(den.x);
    r.y = __builtin_amdgcn_rcpf(den.y);
    return v * r;
}

// max over the 16 contiguous lanes of a DPP row (e = lane&15), VALU-only.
__device__ __forceinline__ float dpp_rowmax16(float v) {
    int x = __float_as_int(v);
    v = fmaxf(v, __int_as_float(__builtin_amdgcn_mov_dpp(x, 0xB1, 0xF, 0xF, true)));
    x = __float_as_int(v);
    v = fmaxf(v, __int_as_float(__builtin_amdgcn_mov_dpp(x, 0x4E, 0xF, 0xF, true)));
    x = __float_as_int(v);
    v = fmaxf(v, __int_as_float(__builtin_amdgcn_mov_dpp(x, 0x141, 0xF, 0xF, true)));
    x = __float_as_int(v);
    v = fmaxf(v, __int_as_float(__builtin_amdgcn_mov_dpp(x, 0x140, 0xF, 0xF, true)));
    return v;
}

// ---------------------------------------------------------------------------
// Kernel 1: kNN top-16 via branch-free radix select (one wave per query).
// ---------------------------------------------------------------------------
__global__ __launch_bounds__(512) void knn_select_kernel(const float* __restrict__ coords,
                                                         int* __restrict__ knn_out) {
    __shared__ float lc[3][N_];
    __shared__ float lsq[N_];
    __shared__ int cnt[8];
    const int wave = threadIdx.x >> 6;
    const int lane = threadIdx.x & 63;
    const int p = blockIdx.x * 8 + wave;
    const int b = p >> 11;
    const int n0 = p & (N_ - 1);
    const float* cb = coords + (size_t)b * N_ * 3;
    for (int i = threadIdx.x; i < N_ * 3; i += 512) {
        int n = i / 3, c = i - 3 * n;
        lc[c][n] = cb[i];
    }
    __syncthreads();
    for (int n = threadIdx.x; n < N_; n += 512) lsq[n] = sq3_ref(lc[0][n], lc[1][n], lc[2][n]);
    __syncthreads();

    const float qx = lc[0][n0], qy = lc[1][n0], qz = lc[2][n0], sqq = lsq[n0];
    unsigned key[32];
#pragma unroll
    for (int j = 0; j < 32; ++j) {
        const int m = j * 64 + lane;
        key[j] = __float_as_uint(d2_ref(qx, qy, qz, sqq, lc[0][m], lc[1][m], lc[2][m], lsq[m]));
    }

    unsigned prefix = 0;
    int rem = K_, setc = N_, bshift = 0;
    bool bounded = false;
    for (int bit = 31; bit >= 0; --bit) {
        const unsigned want = prefix << 1;
        int c = 0;
#pragma unroll
        for (int j = 0; j < 32; ++j) c += ((key[j] >> bit) == want) ? 1 : 0;
        for (int off = 1; off < 64; off <<= 1) c += __shfl_xor(c, off, 64);
        if (rem <= c) { prefix = want; setc = c; }
        else          { prefix = want | 1u; rem -= c; setc -= c; }
        bshift = bit;
        if (setc == rem) { bounded = true; break; }
    }

    if (lane == 0) cnt[wave] = 0;
    int* op = knn_out + (size_t)p * K_;
    const unsigned long long BE = bounded ? (((unsigned long long)prefix + 1ull) << bshift)
                                          : (unsigned long long)prefix;
#pragma unroll
    for (int j = 0; j < 32; ++j) {
        if ((unsigned long long)key[j] < BE) {
            int s = atomicAdd(&cnt[wave], 1);
            op[s] = j * 64 + lane;
        }
    }
    if (!bounded) {
        const unsigned V = prefix;
#pragma unroll
        for (int j = 0; j < 32; ++j) {
            if (rem > 0) {
                unsigned long long mask = __ballot(key[j] == V);
                int below = __popcll(mask & ((1ull << lane) - 1ull));
                if (key[j] == V && below < rem) {
                    int s = atomicAdd(&cnt[wave], 1);
                    op[s] = j * 64 + lane;
                }
                rem -= __popcll(mask);
            }
        }
    }
}

// ---------------------------------------------------------------------------
// Kernel 2: prepack W1/W2/W3/Ws into bf16 MFMA A-fragments, CHUNK-MAJOR:
// chunk c (16 KiB) = fragments [16c..16c+15] (= mt 0..15 of one kt).
//   fragment (c,mt): W[32kt + 8g + i][16mt + e]; c = L*8+kt, 24+kt (Ws).
// ---------------------------------------------------------------------------
__global__ __launch_bounds__(64) void wprep_kernel(const float* __restrict__ W1,
                                                   const float* __restrict__ W2,
                                                   const float* __restrict__ W3,
                                                   const float* __restrict__ Ws,
                                                   short* __restrict__ WF) {
    const int bi = blockIdx.x;          // 0..447
    const int lane = threadIdx.x;
    const int g = lane >> 4, e = lane & 15;
    const float* W;
    int mt, kt;
    if (bi < 384) {
        const int L = bi >> 7;
        const int t = bi & 127;         // t = kt*16 + mt
        kt = t >> 4; mt = t & 15;
        W = (L == 0) ? W1 : (L == 1) ? W2 : W3;
    } else {
        const int t = bi - 384;
        kt = t >> 4; mt = t & 15;
        W = Ws;
    }
    const int f = 16 * mt + e;
    unsigned v[4];
#pragma unroll
    for (int i2 = 0; i2 < 4; ++i2) {
        const int k = 32 * kt + 8 * g + 2 * i2;
        v[i2] = pack2(W[(size_t)k * E_ + f], W[(size_t)(k + 1) * E_ + f]);
    }
    uint4 u; u.x = v[0]; u.y = v[1]; u.z = v[2]; u.w = v[3];
    *reinterpret_cast<uint4*>(WF + ((size_t)bi * 64 + lane) * 8) = u;
}

// ---------------------------------------------------------------------------
// Kernel 2b: shortcut precompute. out[p][f] = (x @ Ws)[p][f] + bs[f], f32.
// One wave = 16 points (B cols = points); A = WF chunks 24..27.
// C layout: col = lane&15 = point, row = 4*(lane>>4)+i = feature-in-tile.
// d_out is fully overwritten here, then read-modify-written by edgeconv.
// ---------------------------------------------------------------------------
__global__ __launch_bounds__(256) void shortcut_kernel(const float* __restrict__ x,
                                                       const short* __restrict__ WF,
                                                       const float* __restrict__ bs,
                                                       float* __restrict__ out) {
    const int wave = threadIdx.x >> 6;
    const int lane = threadIdx.x & 63;
    const int e = lane & 15;
    const int g = lane >> 4;
    const int p0 = (blockIdx.x * 4 + wave) * 16;     // 16 points per wave
    const float* xr = x + (size_t)(p0 + e) * D_;
    const short* WSF = WF + (size_t)(24 * 16) * 512;

    f32x4 acc[16];
    const f32x4 z4 = {0.f, 0.f, 0.f, 0.f};
#pragma unroll
    for (int mt = 0; mt < 16; ++mt) acc[mt] = z4;

#pragma unroll
    for (int kt = 0; kt < 4; ++kt) {
        const float4 xa = *(const float4*)(xr + kt * 32 + g * 8);
        const float4 xb = *(const float4*)(xr + kt * 32 + g * 8 + 4);
        union { unsigned u[4]; bf16x8 v; } bx;
        bx.u[0] = pack2(xa.x, xa.y); bx.u[1] = pack2(xa.z, xa.w);
        bx.u[2] = pack2(xb.x, xb.y); bx.u[3] = pack2(xb.z, xb.w);
#pragma unroll
        for (int mt = 0; mt < 16; ++mt) {
            const bf16x8 a = *(const bf16x8*)(WSF + ((size_t)(kt * 16 + mt) * 64 + lane) * 8);
            acc[mt] = __builtin_amdgcn_mfma_f32_16x16x32_bf16(a, bx.v, acc[mt], 0, 0, 0);
        }
    }
#pragma unroll
    for (int mt = 0; mt < 16; ++mt) {
        const float4 bsv = *(const float4*)(bs + 16 * mt + 4 * g);
        float4 o;
        o.x = acc[mt][0] + bsv.x; o.y = acc[mt][1] + bsv.y;
        o.z = acc[mt][2] + bsv.z; o.w = acc[mt][3] + bsv.w;
        *(float4*)(out + (size_t)(p0 + e) * E_ + 16 * mt + 4 * g) = o;
    }
}

// ---------------------------------------------------------------------------
// Kernel 3: fused edge-MLP, WAVE-PAIR mt-split (R8/R9 structure), shortcut
// phases removed (precomputed into d_out by shortcut_kernel).
// ---------------------------------------------------------------------------
#define WCHUNKS 24

__device__ __forceinline__ void stage_chunk(const short* __restrict__ WF,
                                            short* __restrict__ dst,
                                            int c, int wave, int lane) {
    const short* src = WF + ((size_t)(c << 4) << 9);    // fragment 16c, *512 shorts
#pragma unroll
    for (int i = 0; i < 4; ++i) {
        const int slot = (i << 8) + (wave << 6);        // wave-uniform slot base
        const short* gp = src + ((size_t)(slot + lane) << 3);
        short* lp = dst + ((size_t)slot << 3);
        __builtin_amdgcn_global_load_lds(
            (const __attribute__((address_space(1))) void*)gp,
            (__attribute__((address_space(3))) void*)lp, 16, 0, 0);
    }
}

__global__ __launch_bounds__(256, 2) void edgeconv_mfma(
    const float* __restrict__ x, const int* __restrict__ knn,
    const short* __restrict__ WF,
    const float* __restrict__ b1, const float* __restrict__ g1, const float* __restrict__ be1,
    const float* __restrict__ b2, const float* __restrict__ g2, const float* __restrict__ be2,
    const float* __restrict__ b3, const float* __restrict__ g3, const float* __restrict__ be3,
    float* __restrict__ out)
{
    __shared__ short Hl[2][2][4096];    // 32 KiB: [pair][point][16e x 256f bf16] swizzled
    __shared__ short Wbuf[2][8192];     // 32 KiB: double-buffered 16 KiB W chunks
    __shared__ float4 Xch[2][2][16];    // 1 KiB: LN partial exchange (s0,q0,s1,q1)
    __shared__ float Pl[9 * 256];       // 9 KiB: b1,g1,be1,b2,g2,be2,b3,g3,be3
    const int tid  = threadIdx.x;
    const int wave = tid >> 6;
    const int lane = tid & 63;
    const int wq = wave & 1;            // parity within pair (feature-half owner)
    const int pr = wave >> 1;           // pair index
    const int e = lane & 15;
    const int g = lane >> 4;
    const int p = blockIdx.x * 4 + wave;   // own point
    const int b = p >> 11;
    const int n = p & (N_ - 1);
    const unsigned swz = (unsigned)((e & 7) << 4);
    char* Hown = (char*)&Hl[pr][wq][0];
    char* Hp0  = (char*)&Hl[pr][0][0];
    char* Hp1  = (char*)&Hl[pr][1][0];

    // issue chunk-0 staging first so it flies under the H build
    stage_chunk(WF, &Wbuf[0][0], 0, wave, lane);

    // stage LN params once per block
    {
        const float* srcs[9] = {b1, g1, be1, b2, g2, be2, b3, g3, be3};
#pragma unroll
        for (int a = 0; a < 9; ++a) Pl[a * 256 + tid] = srcs[a][tid];
    }

    // ---- edge build (own point): H[e][0:128]=central, H[e][128:256]=nbr-central
    {
        const float4* xr = (const float4*)(x + ((size_t)b * N_ + n) * D_);
        const int nb = knn[(size_t)p * K_ + e];
        const float4* nr = (const float4*)(x + ((size_t)b * N_ + nb) * D_);
#pragma unroll
        for (int c2 = 0; c2 < 8; ++c2) {
            const float4 cv = xr[8 * g + c2];
            const float4 nv = nr[8 * g + c2];
            const int base = (e << 9) + (g << 6) + (c2 << 3);
            *(uint2*)(Hown + (base ^ swz)) = make_uint2(pack2(cv.x, cv.y), pack2(cv.z, cv.w));
            *(uint2*)(Hown + ((base + 256) ^ swz)) =
                make_uint2(pack2(nv.x - cv.x, nv.y - cv.y), pack2(nv.z - cv.z, nv.w - cv.w));
        }
    }

    f32x4 acc0[8], acc1[8];             // [mtl] for point0 / point1
    int pb = 0;
    const f32x4 z4 = {0.f, 0.f, 0.f, 0.f};

    for (int L = 0; L < 3; ++L) {
        const float* PlL = &Pl[L * 768];
#pragma unroll
        for (int mtl = 0; mtl < 8; ++mtl) { acc0[mtl] = z4; acc1[mtl] = z4; }

        for (int kt = 0; kt < 8; ++kt) {
            const int c = L * 8 + kt;
            asm volatile("s_waitcnt vmcnt(0)" ::: "memory");
            __syncthreads();
            if (c + 1 < WCHUNKS) stage_chunk(WF, &Wbuf[pb ^ 1][0], c + 1, wave, lane);
            const int offB = (int)((unsigned)((e << 9) + (kt << 6) + (g << 4)) ^ swz);
            const bf16x8 Bc0 = *(const bf16x8*)(Hp0 + offB);
            const bf16x8 Bc1 = *(const bf16x8*)(Hp1 + offB);
            const short* Wc = &Wbuf[pb][0];
            __builtin_amdgcn_s_setprio(1);
#pragma unroll
            for (int mtl = 0; mtl < 8; ++mtl) {
                const bf16x8 a = *(const bf16x8*)(Wc + ((((wq << 3) + mtl) << 6) + lane) * 8);
                acc0[mtl] = __builtin_amdgcn_mfma_f32_16x16x32_bf16(a, Bc0, acc0[mtl], 0, 0, 0);
                acc1[mtl] = __builtin_amdgcn_mfma_f32_16x16x32_bf16(a, Bc1, acc1[mtl], 0, 0, 0);
            }
            __builtin_amdgcn_s_setprio(0);
            pb ^= 1;
        }

        // ---- LN pass 1: bias + partial sums (pk form) ----
        f32x2 s2_0 = {0.f, 0.f}, q2_0 = {0.f, 0.f};
        f32x2 s2_1 = {0.f, 0.f}, q2_1 = {0.f, 0.f};
#pragma unroll
        for (int mtl = 0; mtl < 8; ++mtl) {
            const int mtg = (wq << 3) + mtl;
            const float4 bv = *(const float4*)(PlL + mtg * 16 + (g << 2));
            const f32x2 blo = {bv.x, bv.y}, bhi = {bv.z, bv.w};
            f32x2 a0lo = {acc0[mtl][0], acc0[mtl][1]};
            f32x2 a0hi = {acc0[mtl][2], acc0[mtl][3]};
            f32x2 a1lo = {acc1[mtl][0], acc1[mtl][1]};
            f32x2 a1hi = {acc1[mtl][2], acc1[mtl][3]};
            a0lo = a0lo + blo; a0hi = a0hi + bhi;
            a1lo = a1lo + blo; a1hi = a1hi + bhi;
            s2_0 = s2_0 + a0lo; s2_0 = s2_0 + a0hi;
            q2_0 = q2_0 + a0lo * a0lo; q2_0 = q2_0 + a0hi * a0hi;
            s2_1 = s2_1 + a1lo; s2_1 = s2_1 + a1hi;
            q2_1 = q2_1 + a1lo * a1lo; q2_1 = q2_1 + a1hi * a1hi;
            acc0[mtl][0] = a0lo.x; acc0[mtl][1] = a0lo.y;
            acc0[mtl][2] = a0hi.x; acc0[mtl][3] = a0hi.y;
            acc1[mtl][0] = a1lo.x; acc1[mtl][1] = a1lo.y;
            acc1[mtl][2] = a1hi.x; acc1[mtl][3] = a1hi.y;
        }
        float s0 = s2_0.x + s2_0.y, q0 = q2_0.x + q2_0.y;
        float s1 = s2_1.x + s2_1.y, q1 = q2_1.x + q2_1.y;
        s0 += __shfl_xor(s0, 16, 64); s0 += __shfl_xor(s0, 32, 64);
        q0 += __shfl_xor(q0, 16, 64); q0 += __shfl_xor(q0, 32, 64);
        s1 += __shfl_xor(s1, 16, 64); s1 += __shfl_xor(s1, 32, 64);
        q1 += __shfl_xor(q1, 16, 64); q1 += __shfl_xor(q1, 32, 64);
        if (lane < 16) Xch[pr][wq][e] = make_float4(s0, q0, s1, q1);
        __syncthreads();
        const float4 oX = Xch[pr][wq ^ 1][e];
        const float mu0 = (s0 + oX.x) * (1.0f / 256.0f);
        const float var0 = fmaf(-mu0, mu0, (q0 + oX.y) * (1.0f / 256.0f));
        const float rstd0 = rsqrtf(var0 + LN_EPS);
        const float mu1 = (s1 + oX.z) * (1.0f / 256.0f);
        const float var1 = fmaf(-mu1, mu1, (q1 + oX.w) * (1.0f / 256.0f));
        const float rstd1 = rsqrtf(var1 + LN_EPS);

        // ---- LN pass 2 + GELU (pk form) ----
#pragma unroll
        for (int mtl = 0; mtl < 8; ++mtl) {
            const int mtg = (wq << 3) + mtl;
            const float4 gv  = *(const float4*)(PlL + 256 + mtg * 16 + (g << 2));
            const float4 bev = *(const float4*)(PlL + 512 + mtg * 16 + (g << 2));
            const f32x2 glo = {gv.x, gv.y}, ghi = {gv.z, gv.w};
            const f32x2 belo = {bev.x, bev.y}, behi = {bev.z, bev.w};
            const f32x2 A0lo = glo * rstd0, A0hi = ghi * rstd0;
            const f32x2 C0lo = A0lo * (-mu0) + belo, C0hi = A0hi * (-mu0) + behi;
            const f32x2 v0lo = {acc0[mtl][0], acc0[mtl][1]};
            const f32x2 v0hi = {acc0[mtl][2], acc0[mtl][3]};
            const f32x2 r0lo = gelu2(v0lo * A0lo + C0lo);
            const f32x2 r0hi = gelu2(v0hi * A0hi + C0hi);
            const f32x2 A1lo = glo * rstd1, A1hi = ghi * rstd1;
            const f32x2 C1lo = A1lo * (-mu1) + belo, C1hi = A1hi * (-mu1) + behi;
            const f32x2 v1lo = {acc1[mtl][0], acc1[mtl][1]};
            const f32x2 v1hi = {acc1[mtl][2], acc1[mtl][3]};
            const f32x2 r1lo = gelu2(v1lo * A1lo + C1lo);
            const f32x2 r1hi = gelu2(v1hi * A1hi + C1hi);
            if (L < 2) {
                const int wb = (int)((unsigned)((e << 9) + (mtg << 5) + (g << 3)) ^ swz);
                *(uint2*)(Hp0 + wb) = make_uint2(pack2(r0lo.x, r0lo.y), pack2(r0hi.x, r0hi.y));
                *(uint2*)(Hp1 + wb) = make_uint2(pack2(r1lo.x, r1lo.y), pack2(r1hi.x, r1hi.y));
            } else {
                acc0[mtl][0] = r0lo.x; acc0[mtl][1] = r0lo.y;
                acc0[mtl][2] = r0hi.x; acc0[mtl][3] = r0hi.y;
                acc1[mtl][0] = r1lo.x; acc1[mtl][1] = r1lo.y;
                acc1[mtl][2] = r1hi.x; acc1[mtl][3] = r1hi.y;
            }
        }
        // next phase's __syncthreads makes H writes visible before B reads
    }

    // ---- max over 16 edges (DPP row reduce) + bounce to Sb (Hl is dead) ----
#pragma unroll
    for (int mtl = 0; mtl < 8; ++mtl) {
#pragma unroll
        for (int i = 0; i < 4; ++i) {
            acc0[mtl][i] = dpp_rowmax16(acc0[mtl][i]);
            acc1[mtl][i] = dpp_rowmax16(acc1[mtl][i]);
        }
    }
    float* Sb0 = (float*)Hp0;
    float* Sb1 = (float*)Hp1;
#pragma unroll
    for (int mtl = 0; mtl < 8; ++mtl) {
        if (e == mtl) {
            const int fo = (((wq << 3) + mtl) << 4) + (g << 2);
            *(float4*)(Sb0 + fo) = *(const float4*)&acc0[mtl];
            *(float4*)(Sb1 + fo) = *(const float4*)&acc1[mtl];
        }
    }
    __syncthreads();

    // ---- final epilogue: agg from Sb, shortcut (incl bs) from d_out ----
    const int f0 = 16 * e + (g << 2);
    const float* SbO = wq ? Sb1 : Sb0;
    const float4 agg = *(const float4*)(SbO + f0);
    float* op = out + (size_t)p * E_ + f0;
    const float4 ssc = *(const float4*)op;
    f32x2 elo = {agg.x + ssc.x, agg.y + ssc.y};
    f32x2 ehi = {agg.z + ssc.z, agg.w + ssc.w};
    const f32x2 olo = gelu2(elo);
    const f32x2 ohi = gelu2(ehi);
    float4 o;
    o.x = olo.x; o.y = olo.y; o.z = ohi.x; o.w = ohi.y;
    *(float4*)op = o;
}

extern "C" void kernel_launch(void* const* d_in, const int* in_sizes, int n_in,
                              void* d_out, int out_size, void* d_ws, size_t ws_size,
                              hipStream_t stream) {
    const float* x      = (const float*)d_in[0];
    const float* coords = (const float*)d_in[1];
    const float* W1  = (const float*)d_in[2];
    const float* b1  = (const float*)d_in[3];
    const float* g1  = (const float*)d_in[4];
    const float* be1 = (const float*)d_in[5];
    const float* W2  = (const float*)d_in[6];
    const float* b2  = (const float*)d_in[7];
    const float* g2  = (const float*)d_in[8];
    const float* be2 = (const float*)d_in[9];
    const float* W3  = (const float*)d_in[10];
    const float* b3  = (const float*)d_in[11];
    const float* g3  = (const float*)d_in[12];
    const float* be3 = (const float*)d_in[13];
    const float* Ws  = (const float*)d_in[14];
    const float* bs  = (const float*)d_in[15];
    float* out = (float*)d_out;

    int*   knn = (int*)d_ws;                          // 1 MiB
    short* WF  = (short*)((char*)d_ws + (1 << 20));   // 448 KiB bf16 fragments

    wprep_kernel<<<448, 64, 0, stream>>>(W1, W2, W3, Ws, WF);
    knn_select_kernel<<<B_ * (N_ / 8), 512, 0, stream>>>(coords, knn);
    shortcut_kernel<<<(B_ * N_) / 64, 256, 0, stream>>>(x, WF, bs, out);
    edgeconv_mfma<<<(B_ * N_) / 4, 256, 0, stream>>>(
        x, knn, WF, b1, g1, be1, b2, g2, be2, b3, g3, be3, out);
}